// Round 2
// baseline (573.409 us; speedup 1.0000x reference)
//
#include <hip/hip_runtime.h>
#include <hip/hip_bf16.h>

// B=8, L=4096, C=384, h=8, d=48, H=W=64
// Inputs/outputs fp32 (per reference). Internals: qkv/y bf16 (ws),
// sumsq/G/invnorm/attn2 fp32 (ws). Final out + attn written fp32.

typedef __bf16 bf16x8 __attribute__((ext_vector_type(8)));
typedef float f32x4 __attribute__((ext_vector_type(4)));

__device__ inline __bf16 f2b(float f) {
    __hip_bfloat16 h = __float2bfloat16(f);
    __bf16 r; __builtin_memcpy(&r, &h, 2); return r;
}
__device__ inline float b2f(__hip_bfloat16 h) { return __bfloat162float(h); }

// load 8 contiguous elements as bf16x8 (16B-aligned source)
__device__ inline bf16x8 load8(const __hip_bfloat16* p) {
    uint4 v = *(const uint4*)p;
    bf16x8 r; __builtin_memcpy(&r, &v, 16); return r;
}
__device__ inline bf16x8 load8(const float* p) {
    float4 a = *(const float4*)p;
    float4 b = *(const float4*)(p + 4);
    bf16x8 r;
    r[0] = f2b(a.x); r[1] = f2b(a.y); r[2] = f2b(a.z); r[3] = f2b(a.w);
    r[4] = f2b(b.x); r[5] = f2b(b.y); r[6] = f2b(b.z); r[7] = f2b(b.w);
    return r;
}

__device__ inline void storef(float* p, float v) { *p = v; }
__device__ inline void storef(__hip_bfloat16* p, float v) { *p = __float2bfloat16(v); }

// ---------------------------------------------------------------------------
// GEMM: C[M,N] = A[M,K] @ Bw[N,K]^T + bias[N]  (bf16 MFMA, fp32 accum)
// Block tile 128x64, 4 waves, each wave 32 rows x 64 cols (2x4 MFMA 16x16x32).
// ---------------------------------------------------------------------------
template <typename TA, typename TO>
__global__ __launch_bounds__(256) void gemm_nt_bias(
    const TA* __restrict__ A,
    const float* __restrict__ Bw,
    const float* __restrict__ bias,
    TO* __restrict__ C,
    int M, int N, int K)
{
    __shared__ short As[128][56];   // row stride 112B -> 2-way max aliasing on b128 reads
    __shared__ short Bs[64][56];
    const int t  = threadIdx.x;
    const int m0 = blockIdx.y * 128;
    const int n0 = blockIdx.x * 64;
    const int lane = t & 63;
    const int w    = t >> 6;
    const int r16  = lane & 15;
    const int kb   = (lane >> 4) * 8;

    f32x4 acc[2][4];
    #pragma unroll
    for (int i = 0; i < 2; ++i)
        #pragma unroll
        for (int c = 0; c < 4; ++c)
            acc[i][c] = (f32x4){0.f, 0.f, 0.f, 0.f};

    for (int k0 = 0; k0 < K; k0 += 32) {
        // stage A tile 128x32 (512 8-elem chunks, 2/thread)
        #pragma unroll
        for (int p = 0; p < 2; ++p) {
            int chunk = t + p * 256;
            int row = chunk >> 2;
            int cg  = chunk & 3;
            bf16x8 v = load8(A + (size_t)(m0 + row) * K + k0 + cg * 8);
            *(bf16x8*)&As[row][cg * 8] = v;
        }
        // stage B tile 64x32 (256 chunks, 1/thread)
        {
            int row = t >> 2;
            int cg  = t & 3;
            bf16x8 v = load8(Bw + (size_t)(n0 + row) * K + k0 + cg * 8);
            *(bf16x8*)&Bs[row][cg * 8] = v;
        }
        __syncthreads();
        bf16x8 af[2], bfr[4];
        #pragma unroll
        for (int i = 0; i < 2; ++i)
            af[i] = *(const bf16x8*)&As[w * 32 + i * 16 + r16][kb];
        #pragma unroll
        for (int c = 0; c < 4; ++c)
            bfr[c] = *(const bf16x8*)&Bs[c * 16 + r16][kb];
        #pragma unroll
        for (int i = 0; i < 2; ++i)
            #pragma unroll
            for (int c = 0; c < 4; ++c)
                acc[i][c] = __builtin_amdgcn_mfma_f32_16x16x32_bf16(af[i], bfr[c], acc[i][c], 0, 0, 0);
        __syncthreads();
    }

    const int q4 = (lane >> 4) * 4;
    #pragma unroll
    for (int c = 0; c < 4; ++c) {
        int col = n0 + c * 16 + r16;
        float bv = bias[col];
        #pragma unroll
        for (int i = 0; i < 2; ++i) {
            #pragma unroll
            for (int reg = 0; reg < 4; ++reg) {
                int row = m0 + w * 32 + i * 16 + q4 + reg;
                storef(&C[(size_t)row * N + col], acc[i][c][reg] + bv);
            }
        }
    }
}

// ---------------------------------------------------------------------------
// Column sum-of-squares over L for q,k (cols 0..767 of qkv). Atomic partials.
// ---------------------------------------------------------------------------
__global__ __launch_bounds__(256) void colsumsq_kernel(
    const __hip_bfloat16* __restrict__ qkv, float* __restrict__ sumsq)
{
    int b  = blockIdx.y;
    int l0 = blockIdx.x * 64;
    int t  = threadIdx.x;
    const __hip_bfloat16* base = qkv + (size_t)(b * 4096 + l0) * 1152;
    #pragma unroll
    for (int p = 0; p < 3; ++p) {
        int c = p * 256 + t;
        float acc = 0.f;
        for (int r = 0; r < 64; ++r) {
            float v = b2f(base[(size_t)r * 1152 + c]);
            acc += v * v;
        }
        atomicAdd(&sumsq[b * 768 + c], acc);
    }
}

__global__ void invnorm_kernel(const float* __restrict__ sumsq, float* __restrict__ invn)
{
    int i = blockIdx.x * 256 + threadIdx.x;
    if (i < 6144) invn[i] = 1.f / fmaxf(sqrtf(sumsq[i]), 1e-12f);
}

// ---------------------------------------------------------------------------
// G[bh] = k^T v (48x48, K-slice of 512 per block), atomic fp32 accumulation.
// ---------------------------------------------------------------------------
__global__ __launch_bounds__(256) void ktv_kernel(
    const __hip_bfloat16* __restrict__ qkv, float* __restrict__ G)
{
    __shared__ __hip_bfloat16 ks[64][48];
    __shared__ __hip_bfloat16 vs[64][48];
    int bh = blockIdx.y; int b = bh >> 3; int h = bh & 7;
    int l0 = blockIdx.x * 512;
    int t  = threadIdx.x;
    int ti = t >> 4, tj = t & 15;
    float acc[3][3] = {};
    const __hip_bfloat16* kbase = qkv + 384 + h * 48;
    const __hip_bfloat16* vbase = qkv + 768 + h * 48;
    for (int lt = 0; lt < 512; lt += 64) {
        __syncthreads();
        for (int c = t; c < 384; c += 256) {
            int row = c / 6, cg = c % 6;
            size_t goff = (size_t)(b * 4096 + l0 + lt + row) * 1152 + cg * 8;
            *(uint4*)&ks[row][cg * 8] = *(const uint4*)(kbase + goff);
            *(uint4*)&vs[row][cg * 8] = *(const uint4*)(vbase + goff);
        }
        __syncthreads();
        for (int l = 0; l < 64; ++l) {
            float kv[3], vv[3];
            #pragma unroll
            for (int a = 0; a < 3; ++a) {
                kv[a] = b2f(ks[l][ti * 3 + a]);
                vv[a] = b2f(vs[l][tj * 3 + a]);
            }
            #pragma unroll
            for (int a = 0; a < 3; ++a)
                #pragma unroll
                for (int e = 0; e < 3; ++e)
                    acc[a][e] += kv[a] * vv[e];
        }
    }
    float* Gb = G + (size_t)bh * 2304;
    #pragma unroll
    for (int a = 0; a < 3; ++a)
        #pragma unroll
        for (int e = 0; e < 3; ++e)
            atomicAdd(&Gb[(ti * 3 + a) * 48 + tj * 3 + e], acc[a][e]);
}

// ---------------------------------------------------------------------------
// attn = G * invnorm_k[d] * temp[h] -> fp32 out;  attn2 = attn * invnorm_q[d]
// ---------------------------------------------------------------------------
__global__ void scale_attn_kernel(
    const float* __restrict__ G, const float* __restrict__ invn,
    const float* __restrict__ temp,
    float* __restrict__ attn_out, float* __restrict__ attn2)
{
    int bh = blockIdx.x; int b = bh >> 3; int h = bh & 7;
    float tf = temp[h];
    int t = threadIdx.x;
    for (int e = t; e < 2304; e += 256) {
        int dk = e / 48;
        float ink = invn[b * 768 + 384 + h * 48 + dk];
        float inq = invn[b * 768 + h * 48 + dk];
        float av  = G[(size_t)bh * 2304 + e] * ink * tf;
        attn_out[(size_t)bh * 2304 + e] = av;
        attn2[(size_t)bh * 2304 + e]    = av * inq;
    }
}

// ---------------------------------------------------------------------------
// y[b,l,h*48+e] = sum_d q[b,h,l,d]*attn2[d,e] + lepe(v) ; lepe = dw 3x3 conv
// ---------------------------------------------------------------------------
__global__ __launch_bounds__(256) void qattn_lepe_kernel(
    const __hip_bfloat16* __restrict__ qkv, const float* __restrict__ attn2,
    const float* __restrict__ conv_w, const float* __restrict__ conv_b,
    __hip_bfloat16* __restrict__ y)
{
    __shared__ float a2[48][48];
    __shared__ __hip_bfloat16 qs[32][48];
    __shared__ float cw[48][9];
    __shared__ float cb[48];
    int bh = blockIdx.y; int b = bh >> 3; int h = bh & 7;
    int l0 = blockIdx.x * 32;
    int t  = threadIdx.x;
    for (int i = t; i < 2304; i += 256) a2[i / 48][i % 48] = attn2[(size_t)bh * 2304 + i];
    for (int c = t; c < 192; c += 256) {
        int row = c / 6, cg = c % 6;
        *(uint4*)&qs[row][cg * 8] =
            *(const uint4*)(qkv + (size_t)(b * 4096 + l0 + row) * 1152 + h * 48 + cg * 8);
    }
    if (t < 48) {
        #pragma unroll
        for (int tap = 0; tap < 9; ++tap)
            cw[t][tap] = conv_w[(h * 48 + t) * 9 + tap];
        cb[t] = conv_b[h * 48 + t];
    }
    __syncthreads();
    const __hip_bfloat16* vb = qkv + (size_t)b * 4096 * 1152 + 768 + h * 48;
    for (int idx = t; idx < 1536; idx += 256) {
        int ll = idx / 48, e = idx % 48;
        int l  = l0 + ll;
        int yi = l >> 6, xi = l & 63;
        float acc = cb[e];
        #pragma unroll
        for (int d = 0; d < 48; ++d)
            acc += b2f(qs[ll][d]) * a2[d][e];
        #pragma unroll
        for (int dy = 0; dy < 3; ++dy) {
            int yy = yi + dy - 1;
            if (yy < 0 || yy >= 64) continue;
            #pragma unroll
            for (int dx = 0; dx < 3; ++dx) {
                int xx = xi + dx - 1;
                if (xx < 0 || xx >= 64) continue;
                acc += b2f(vb[(size_t)(yy * 64 + xx) * 1152 + e]) * cw[e][dy * 3 + dx];
            }
        }
        y[(size_t)(b * 4096 + l) * 384 + h * 48 + e] = __float2bfloat16(acc);
    }
}

// ---------------------------------------------------------------------------
extern "C" void kernel_launch(void* const* d_in, const int* in_sizes, int n_in,
                              void* d_out, int out_size, void* d_ws, size_t ws_size,
                              hipStream_t stream)
{
    const float* x      = (const float*)d_in[0];
    const float* qkv_w  = (const float*)d_in[1];
    const float* qkv_b  = (const float*)d_in[2];
    const float* proj_w = (const float*)d_in[3];
    const float* proj_b = (const float*)d_in[4];
    const float* temp   = (const float*)d_in[5];
    const float* conv_w = (const float*)d_in[6];
    const float* conv_b = (const float*)d_in[7];

    char* ws = (char*)d_ws;
    __hip_bfloat16* qkv = (__hip_bfloat16*)(ws);                 // 32768*1152*2 = 75,497,472
    __hip_bfloat16* yb  = (__hip_bfloat16*)(ws + 75497472);      // 32768*384*2  = 25,165,824
    float* sumsq = (float*)(ws + 100663296);                     // 24,576 B
    float* G     = (float*)(ws + 100687872);                     // 589,824 B
    float* invn  = (float*)(ws + 101277696);                     // 24,576 B
    float* attn2 = (float*)(ws + 101302272);                     // 589,824 B

    float* out      = (float*)d_out;
    float* attn_out = out + 12582912;

    // zero the atomic accumulators (sumsq + G are contiguous)
    hipMemsetAsync(ws + 100663296, 0, 614400, stream);

    // 1) qkv = x @ qkv_w^T + qkv_b   (fp32 in -> bf16 out)
    gemm_nt_bias<float, __hip_bfloat16><<<dim3(18, 256), 256, 0, stream>>>(
        x, qkv_w, qkv_b, qkv, 32768, 1152, 384);
    // 2) column sumsq of q,k over L
    colsumsq_kernel<<<dim3(64, 8), 256, 0, stream>>>(qkv, sumsq);
    invnorm_kernel<<<24, 256, 0, stream>>>(sumsq, invn);
    // 3) G = k^T v
    ktv_kernel<<<dim3(8, 64), 256, 0, stream>>>(qkv, G);
    // 4) attn (fp32 out) + attn2 (fp32, q-norm folded)
    scale_attn_kernel<<<64, 256, 0, stream>>>(G, invn, temp, attn_out, attn2);
    // 5) y = q @ attn2 + lepe   (bf16 out)
    qattn_lepe_kernel<<<dim3(128, 64), 256, 0, stream>>>(qkv, attn2, conv_w, conv_b, yb);
    // 6) out = y @ proj_w^T + proj_b   (bf16 A -> fp32 out)
    gemm_nt_bias<__hip_bfloat16, float><<<dim3(6, 256), 256, 0, stream>>>(
        yb, proj_w, proj_b, out, 32768, 384, 384);
}

// Round 3
// 353.642 us; speedup vs baseline: 1.6214x; 1.6214x over previous
//
#include <hip/hip_runtime.h>
#include <hip/hip_bf16.h>

// B=8, L=4096, C=384, h=8, d=48, H=W=64
// Inputs/outputs fp32 (per reference). Internals: qkv/y bf16 (ws),
// sumsq/G/invnorm/attn2 fp32 (ws). Final out + attn written fp32.

typedef __bf16 bf16x8 __attribute__((ext_vector_type(8)));
typedef float f32x4 __attribute__((ext_vector_type(4)));

__device__ inline __bf16 f2b(float f) {
    __hip_bfloat16 h = __float2bfloat16(f);
    __bf16 r; __builtin_memcpy(&r, &h, 2); return r;
}
__device__ inline float b2f(__hip_bfloat16 h) { return __bfloat162float(h); }

// load 8 contiguous elements as bf16x8 (16B-aligned source)
__device__ inline bf16x8 load8(const __hip_bfloat16* p) {
    uint4 v = *(const uint4*)p;
    bf16x8 r; __builtin_memcpy(&r, &v, 16); return r;
}
__device__ inline bf16x8 load8(const float* p) {
    float4 a = *(const float4*)p;
    float4 b = *(const float4*)(p + 4);
    bf16x8 r;
    r[0] = f2b(a.x); r[1] = f2b(a.y); r[2] = f2b(a.z); r[3] = f2b(a.w);
    r[4] = f2b(b.x); r[5] = f2b(b.y); r[6] = f2b(b.z); r[7] = f2b(b.w);
    return r;
}

__device__ inline void storef(float* p, float v) { *p = v; }
__device__ inline void storef(__hip_bfloat16* p, float v) { *p = __float2bfloat16(v); }

// ---------------------------------------------------------------------------
// GEMM: C[M,N] = A[M,K] @ Bw[N,K]^T + bias[N]  (bf16 MFMA, fp32 accum)
// Block tile 128x64, 4 waves, each wave 32 rows x 64 cols (2x4 MFMA 16x16x32).
// ---------------------------------------------------------------------------
template <typename TA, typename TO>
__global__ __launch_bounds__(256) void gemm_nt_bias(
    const TA* __restrict__ A,
    const float* __restrict__ Bw,
    const float* __restrict__ bias,
    TO* __restrict__ C,
    int M, int N, int K)
{
    __shared__ short As[128][56];   // row stride 112B -> 2-way max aliasing on b128 reads
    __shared__ short Bs[64][56];
    const int t  = threadIdx.x;
    const int m0 = blockIdx.y * 128;
    const int n0 = blockIdx.x * 64;
    const int lane = t & 63;
    const int w    = t >> 6;
    const int r16  = lane & 15;
    const int kb   = (lane >> 4) * 8;

    f32x4 acc[2][4];
    #pragma unroll
    for (int i = 0; i < 2; ++i)
        #pragma unroll
        for (int c = 0; c < 4; ++c)
            acc[i][c] = (f32x4){0.f, 0.f, 0.f, 0.f};

    for (int k0 = 0; k0 < K; k0 += 32) {
        // stage A tile 128x32 (512 8-elem chunks, 2/thread)
        #pragma unroll
        for (int p = 0; p < 2; ++p) {
            int chunk = t + p * 256;
            int row = chunk >> 2;
            int cg  = chunk & 3;
            bf16x8 v = load8(A + (size_t)(m0 + row) * K + k0 + cg * 8);
            *(bf16x8*)&As[row][cg * 8] = v;
        }
        // stage B tile 64x32 (256 chunks, 1/thread)
        {
            int row = t >> 2;
            int cg  = t & 3;
            bf16x8 v = load8(Bw + (size_t)(n0 + row) * K + k0 + cg * 8);
            *(bf16x8*)&Bs[row][cg * 8] = v;
        }
        __syncthreads();
        bf16x8 af[2], bfr[4];
        #pragma unroll
        for (int i = 0; i < 2; ++i)
            af[i] = *(const bf16x8*)&As[w * 32 + i * 16 + r16][kb];
        #pragma unroll
        for (int c = 0; c < 4; ++c)
            bfr[c] = *(const bf16x8*)&Bs[c * 16 + r16][kb];
        #pragma unroll
        for (int i = 0; i < 2; ++i)
            #pragma unroll
            for (int c = 0; c < 4; ++c)
                acc[i][c] = __builtin_amdgcn_mfma_f32_16x16x32_bf16(af[i], bfr[c], acc[i][c], 0, 0, 0);
        __syncthreads();
    }

    const int q4 = (lane >> 4) * 4;
    #pragma unroll
    for (int c = 0; c < 4; ++c) {
        int col = n0 + c * 16 + r16;
        float bv = bias[col];
        #pragma unroll
        for (int i = 0; i < 2; ++i) {
            #pragma unroll
            for (int reg = 0; reg < 4; ++reg) {
                int row = m0 + w * 32 + i * 16 + q4 + reg;
                storef(&C[(size_t)row * N + col], acc[i][c][reg] + bv);
            }
        }
    }
}

// ---------------------------------------------------------------------------
// Column sum-of-squares over L for q,k (cols 0..767 of qkv). Atomic partials.
// ---------------------------------------------------------------------------
__global__ __launch_bounds__(256) void colsumsq_kernel(
    const __hip_bfloat16* __restrict__ qkv, float* __restrict__ sumsq)
{
    int b  = blockIdx.y;
    int l0 = blockIdx.x * 64;
    int t  = threadIdx.x;
    const __hip_bfloat16* base = qkv + (size_t)(b * 4096 + l0) * 1152;
    #pragma unroll
    for (int p = 0; p < 3; ++p) {
        int c = p * 256 + t;
        float acc = 0.f;
        for (int r = 0; r < 64; ++r) {
            float v = b2f(base[(size_t)r * 1152 + c]);
            acc += v * v;
        }
        atomicAdd(&sumsq[b * 768 + c], acc);
    }
}

__global__ void invnorm_kernel(const float* __restrict__ sumsq, float* __restrict__ invn)
{
    int i = blockIdx.x * 256 + threadIdx.x;
    if (i < 6144) invn[i] = 1.f / fmaxf(sqrtf(sumsq[i]), 1e-12f);
}

// ---------------------------------------------------------------------------
// G[bh] = k^T v  via MFMA.  Grid (4, 64): each block covers 1024 of L for one
// (b,h). 4 waves on disjoint 32-l chunks; k,v tiles staged TRANSPOSED in LDS
// (row stride 40 bf16 = 80B: 16B-aligned rows, 2-way max bank aliasing on
// ds_read_b128). Cross-wave reduce via padded LDS, 4-contender atomicAdd to G.
// ---------------------------------------------------------------------------
__global__ __launch_bounds__(256) void ktv_mfma_kernel(
    const __hip_bfloat16* __restrict__ qkv, float* __restrict__ G)
{
    __shared__ __hip_bfloat16 kT[4][48][40];
    __shared__ __hip_bfloat16 vT[4][48][40];
    __shared__ float red[4][48][49];   // +1 pad: quad rows land on distinct banks

    const int bh = blockIdx.y; const int b = bh >> 3; const int h = bh & 7;
    const int lbase = blockIdx.x * 1024;
    const int t = threadIdx.x;
    const int w = t >> 6, lane = t & 63;
    const int r16 = lane & 15, quad = lane >> 4;

    f32x4 acc[3][3];
    #pragma unroll
    for (int mi = 0; mi < 3; ++mi)
        #pragma unroll
        for (int ni = 0; ni < 3; ++ni)
            acc[mi][ni] = (f32x4){0.f, 0.f, 0.f, 0.f};

    // staging role: thread t stages one (l-row, matrix) pair per iteration
    const int mat  = t & 1;        // 0 = k, 1 = v
    const int lrow = t >> 1;       // 0..127
    const int tile = lrow >> 5, l_in = lrow & 31;
    const __hip_bfloat16* src = qkv + 384 + mat * 384 + h * 48;
    __hip_bfloat16* dstT = (mat ? &vT[0][0][0] : &kT[0][0][0]) + ((size_t)tile * 48 * 40 + l_in);

    for (int it = 0; it < 8; ++it) {
        const int l0 = lbase + it * 128;
        // load one row of 48 bf16 (96B, 6x16B) then write transposed
        const __hip_bfloat16* p = src + (size_t)(b * 4096 + l0 + lrow) * 1152;
        __hip_bfloat16 row[48];
        #pragma unroll
        for (int j = 0; j < 6; ++j) {
            uint4 v = *(const uint4*)(p + j * 8);
            __builtin_memcpy(&row[j * 8], &v, 16);
        }
        #pragma unroll
        for (int d = 0; d < 48; ++d)
            dstT[d * 40] = row[d];
        __syncthreads();

        // wave w computes over its 32-l chunk
        bf16x8 af[3], bfr[3];
        #pragma unroll
        for (int mi = 0; mi < 3; ++mi)
            af[mi] = *(const bf16x8*)&kT[w][mi * 16 + r16][quad * 8];
        #pragma unroll
        for (int ni = 0; ni < 3; ++ni)
            bfr[ni] = *(const bf16x8*)&vT[w][ni * 16 + r16][quad * 8];
        #pragma unroll
        for (int mi = 0; mi < 3; ++mi)
            #pragma unroll
            for (int ni = 0; ni < 3; ++ni)
                acc[mi][ni] = __builtin_amdgcn_mfma_f32_16x16x32_bf16(af[mi], bfr[ni], acc[mi][ni], 0, 0, 0);
        __syncthreads();
    }

    // cross-wave reduction: C/D layout col=lane&15, row=quad*4+reg
    #pragma unroll
    for (int mi = 0; mi < 3; ++mi)
        #pragma unroll
        for (int ni = 0; ni < 3; ++ni)
            #pragma unroll
            for (int reg = 0; reg < 4; ++reg)
                red[w][mi * 16 + quad * 4 + reg][ni * 16 + r16] = acc[mi][ni][reg];
    __syncthreads();

    float* Gb = G + (size_t)bh * 2304;
    for (int cell = t; cell < 2304; cell += 256) {
        int row = cell / 48, col = cell % 48;
        float s = red[0][row][col] + red[1][row][col] + red[2][row][col] + red[3][row][col];
        atomicAdd(&Gb[cell], s);
    }
}

// ---------------------------------------------------------------------------
// attn = G * invnorm_k[d] * temp[h] -> fp32 out;  attn2 = attn * invnorm_q[d]
// ---------------------------------------------------------------------------
__global__ void scale_attn_kernel(
    const float* __restrict__ G, const float* __restrict__ invn,
    const float* __restrict__ temp,
    float* __restrict__ attn_out, float* __restrict__ attn2)
{
    int bh = blockIdx.x; int b = bh >> 3; int h = bh & 7;
    float tf = temp[h];
    int t = threadIdx.x;
    for (int e = t; e < 2304; e += 256) {
        int dk = e / 48;
        float ink = invn[b * 768 + 384 + h * 48 + dk];
        float inq = invn[b * 768 + h * 48 + dk];
        float av  = G[(size_t)bh * 2304 + e] * ink * tf;
        attn_out[(size_t)bh * 2304 + e] = av;
        attn2[(size_t)bh * 2304 + e]    = av * inq;
    }
}

// ---------------------------------------------------------------------------
// y[b,l,h*48+e] = sum_d q[b,h,l,d]*attn2[d,e] + lepe(v) ; lepe = dw 3x3 conv
// ---------------------------------------------------------------------------
__global__ __launch_bounds__(256) void qattn_lepe_kernel(
    const __hip_bfloat16* __restrict__ qkv, const float* __restrict__ attn2,
    const float* __restrict__ conv_w, const float* __restrict__ conv_b,
    __hip_bfloat16* __restrict__ y)
{
    __shared__ float a2[48][48];
    __shared__ __hip_bfloat16 qs[32][48];
    __shared__ float cw[48][9];
    __shared__ float cb[48];
    int bh = blockIdx.y; int b = bh >> 3; int h = bh & 7;
    int l0 = blockIdx.x * 32;
    int t  = threadIdx.x;
    for (int i = t; i < 2304; i += 256) a2[i / 48][i % 48] = attn2[(size_t)bh * 2304 + i];
    for (int c = t; c < 192; c += 256) {
        int row = c / 6, cg = c % 6;
        *(uint4*)&qs[row][cg * 8] =
            *(const uint4*)(qkv + (size_t)(b * 4096 + l0 + row) * 1152 + h * 48 + cg * 8);
    }
    if (t < 48) {
        #pragma unroll
        for (int tap = 0; tap < 9; ++tap)
            cw[t][tap] = conv_w[(h * 48 + t) * 9 + tap];
        cb[t] = conv_b[h * 48 + t];
    }
    __syncthreads();
    const __hip_bfloat16* vb = qkv + (size_t)b * 4096 * 1152 + 768 + h * 48;
    for (int idx = t; idx < 1536; idx += 256) {
        int ll = idx / 48, e = idx % 48;
        int l  = l0 + ll;
        int yi = l >> 6, xi = l & 63;
        float acc = cb[e];
        #pragma unroll
        for (int d = 0; d < 48; ++d)
            acc += b2f(qs[ll][d]) * a2[d][e];
        #pragma unroll
        for (int dy = 0; dy < 3; ++dy) {
            int yy = yi + dy - 1;
            if (yy < 0 || yy >= 64) continue;
            #pragma unroll
            for (int dx = 0; dx < 3; ++dx) {
                int xx = xi + dx - 1;
                if (xx < 0 || xx >= 64) continue;
                acc += b2f(vb[(size_t)(yy * 64 + xx) * 1152 + e]) * cw[e][dy * 3 + dx];
            }
        }
        y[(size_t)(b * 4096 + l) * 384 + h * 48 + e] = __float2bfloat16(acc);
    }
}

// ---------------------------------------------------------------------------
extern "C" void kernel_launch(void* const* d_in, const int* in_sizes, int n_in,
                              void* d_out, int out_size, void* d_ws, size_t ws_size,
                              hipStream_t stream)
{
    const float* x      = (const float*)d_in[0];
    const float* qkv_w  = (const float*)d_in[1];
    const float* qkv_b  = (const float*)d_in[2];
    const float* proj_w = (const float*)d_in[3];
    const float* proj_b = (const float*)d_in[4];
    const float* temp   = (const float*)d_in[5];
    const float* conv_w = (const float*)d_in[6];
    const float* conv_b = (const float*)d_in[7];

    char* ws = (char*)d_ws;
    __hip_bfloat16* qkv = (__hip_bfloat16*)(ws);                 // 32768*1152*2 = 75,497,472
    __hip_bfloat16* yb  = (__hip_bfloat16*)(ws + 75497472);      // 32768*384*2  = 25,165,824
    float* sumsq = (float*)(ws + 100663296);                     // 24,576 B
    float* G     = (float*)(ws + 100687872);                     // 589,824 B
    float* invn  = (float*)(ws + 101277696);                     // 24,576 B
    float* attn2 = (float*)(ws + 101302272);                     // 589,824 B

    float* out      = (float*)d_out;
    float* attn_out = out + 12582912;

    // zero the atomic accumulators (sumsq + G are contiguous)
    hipMemsetAsync(ws + 100663296, 0, 614400, stream);

    // 1) qkv = x @ qkv_w^T + qkv_b   (fp32 in -> bf16 out)
    gemm_nt_bias<float, __hip_bfloat16><<<dim3(18, 256), 256, 0, stream>>>(
        x, qkv_w, qkv_b, qkv, 32768, 1152, 384);
    // 2) column sumsq of q,k over L
    colsumsq_kernel<<<dim3(64, 8), 256, 0, stream>>>(qkv, sumsq);
    invnorm_kernel<<<24, 256, 0, stream>>>(sumsq, invn);
    // 3) G = k^T v  (MFMA)
    ktv_mfma_kernel<<<dim3(4, 64), 256, 0, stream>>>(qkv, G);
    // 4) attn (fp32 out) + attn2 (fp32, q-norm folded)
    scale_attn_kernel<<<64, 256, 0, stream>>>(G, invn, temp, attn_out, attn2);
    // 5) y = q @ attn2 + lepe   (bf16 out)
    qattn_lepe_kernel<<<dim3(128, 64), 256, 0, stream>>>(qkv, attn2, conv_w, conv_b, yb);
    // 6) out = y @ proj_w^T + proj_b   (bf16 A -> fp32 out)
    gemm_nt_bias<__hip_bfloat16, float><<<dim3(6, 256), 256, 0, stream>>>(
        yb, proj_w, proj_b, out, 32768, 384, 384);
}

// Round 5
// 285.510 us; speedup vs baseline: 2.0084x; 1.2386x over previous
//
#include <hip/hip_runtime.h>
#include <hip/hip_bf16.h>

// B=8, L=4096, C=384, h=8, d=48, H=W=64
// Inputs/outputs fp32 (per reference). Internals: qkv/y bf16 (ws),
// sumsq/G/invnorm/attn2 fp32 (ws). Final out + attn written fp32.

typedef __bf16 bf16x8 __attribute__((ext_vector_type(8)));
typedef float f32x4 __attribute__((ext_vector_type(4)));

__device__ inline __bf16 f2b(float f) {
    __hip_bfloat16 h = __float2bfloat16(f);
    __bf16 r; __builtin_memcpy(&r, &h, 2); return r;
}
__device__ inline float b2f(__hip_bfloat16 h) { return __bfloat162float(h); }
__device__ inline float b2f(__bf16 v) {
    __hip_bfloat16 h; __builtin_memcpy(&h, &v, 2); return __bfloat162float(h);
}

// load 8 contiguous elements as bf16x8 (16B-aligned source)
__device__ inline bf16x8 load8(const __hip_bfloat16* p) {
    uint4 v = *(const uint4*)p;
    bf16x8 r; __builtin_memcpy(&r, &v, 16); return r;
}
__device__ inline bf16x8 load8(const float* p) {
    float4 a = *(const float4*)p;
    float4 b = *(const float4*)(p + 4);
    bf16x8 r;
    r[0] = f2b(a.x); r[1] = f2b(a.y); r[2] = f2b(a.z); r[3] = f2b(a.w);
    r[4] = f2b(b.x); r[5] = f2b(b.y); r[6] = f2b(b.z); r[7] = f2b(b.w);
    return r;
}

__device__ inline void storef(float* p, float v) { *p = v; }
__device__ inline void storef(__hip_bfloat16* p, float v) { *p = __float2bfloat16(v); }

// ---------------------------------------------------------------------------
// GEMM: C[M,N] = A[M,K] @ Bw[N,K]^T + bias[N]  (bf16 MFMA, fp32 accum)
// Block tile 128x64, 4 waves, each wave 32 rows x 64 cols (2x4 MFMA 16x16x32).
// ---------------------------------------------------------------------------
template <typename TA, typename TO>
__global__ __launch_bounds__(256) void gemm_nt_bias(
    const TA* __restrict__ A,
    const float* __restrict__ Bw,
    const float* __restrict__ bias,
    TO* __restrict__ C,
    int M, int N, int K)
{
    __shared__ short As[128][56];   // row stride 112B -> 2-way max aliasing on b128 reads
    __shared__ short Bs[64][56];
    const int t  = threadIdx.x;
    const int m0 = blockIdx.y * 128;
    const int n0 = blockIdx.x * 64;
    const int lane = t & 63;
    const int w    = t >> 6;
    const int r16  = lane & 15;
    const int kb   = (lane >> 4) * 8;

    f32x4 acc[2][4];
    #pragma unroll
    for (int i = 0; i < 2; ++i)
        #pragma unroll
        for (int c = 0; c < 4; ++c)
            acc[i][c] = (f32x4){0.f, 0.f, 0.f, 0.f};

    for (int k0 = 0; k0 < K; k0 += 32) {
        // stage A tile 128x32 (512 8-elem chunks, 2/thread)
        #pragma unroll
        for (int p = 0; p < 2; ++p) {
            int chunk = t + p * 256;
            int row = chunk >> 2;
            int cg  = chunk & 3;
            bf16x8 v = load8(A + (size_t)(m0 + row) * K + k0 + cg * 8);
            *(bf16x8*)&As[row][cg * 8] = v;
        }
        // stage B tile 64x32 (256 chunks, 1/thread)
        {
            int row = t >> 2;
            int cg  = t & 3;
            bf16x8 v = load8(Bw + (size_t)(n0 + row) * K + k0 + cg * 8);
            *(bf16x8*)&Bs[row][cg * 8] = v;
        }
        __syncthreads();
        bf16x8 af[2], bfr[4];
        #pragma unroll
        for (int i = 0; i < 2; ++i)
            af[i] = *(const bf16x8*)&As[w * 32 + i * 16 + r16][kb];
        #pragma unroll
        for (int c = 0; c < 4; ++c)
            bfr[c] = *(const bf16x8*)&Bs[c * 16 + r16][kb];
        #pragma unroll
        for (int i = 0; i < 2; ++i)
            #pragma unroll
            for (int c = 0; c < 4; ++c)
                acc[i][c] = __builtin_amdgcn_mfma_f32_16x16x32_bf16(af[i], bfr[c], acc[i][c], 0, 0, 0);
        __syncthreads();
    }

    const int q4 = (lane >> 4) * 4;
    #pragma unroll
    for (int c = 0; c < 4; ++c) {
        int col = n0 + c * 16 + r16;
        float bv = bias[col];
        #pragma unroll
        for (int i = 0; i < 2; ++i) {
            #pragma unroll
            for (int reg = 0; reg < 4; ++reg) {
                int row = m0 + w * 32 + i * 16 + q4 + reg;
                storef(&C[(size_t)row * N + col], acc[i][c][reg] + bv);
            }
        }
    }
}

// ---------------------------------------------------------------------------
// Column sum-of-squares over L for q,k (cols 0..767 of qkv). Atomic partials.
// ---------------------------------------------------------------------------
__global__ __launch_bounds__(256) void colsumsq_kernel(
    const __hip_bfloat16* __restrict__ qkv, float* __restrict__ sumsq)
{
    int b  = blockIdx.y;
    int l0 = blockIdx.x * 64;
    int t  = threadIdx.x;
    const __hip_bfloat16* base = qkv + (size_t)(b * 4096 + l0) * 1152;
    #pragma unroll
    for (int p = 0; p < 3; ++p) {
        int c = p * 256 + t;
        float acc = 0.f;
        for (int r = 0; r < 64; ++r) {
            float v = b2f(base[(size_t)r * 1152 + c]);
            acc += v * v;
        }
        atomicAdd(&sumsq[b * 768 + c], acc);
    }
}

__global__ void invnorm_kernel(const float* __restrict__ sumsq, float* __restrict__ invn)
{
    int i = blockIdx.x * 256 + threadIdx.x;
    if (i < 6144) invn[i] = 1.f / fmaxf(sqrtf(sumsq[i]), 1e-12f);
}

// ---------------------------------------------------------------------------
// G[bh] = k^T v  via MFMA.  Grid (4, 64): each block covers 1024 of L for one
// (b,h). 4 waves on disjoint 32-l chunks; k,v tiles staged TRANSPOSED in LDS.
// ---------------------------------------------------------------------------
__global__ __launch_bounds__(256) void ktv_mfma_kernel(
    const __hip_bfloat16* __restrict__ qkv, float* __restrict__ G)
{
    __shared__ __hip_bfloat16 kT[4][48][40];
    __shared__ __hip_bfloat16 vT[4][48][40];
    __shared__ float red[4][48][49];   // +1 pad: quad rows land on distinct banks

    const int bh = blockIdx.y; const int b = bh >> 3; const int h = bh & 7;
    const int lbase = blockIdx.x * 1024;
    const int t = threadIdx.x;
    const int w = t >> 6, lane = t & 63;
    const int r16 = lane & 15, quad = lane >> 4;

    f32x4 acc[3][3];
    #pragma unroll
    for (int mi = 0; mi < 3; ++mi)
        #pragma unroll
        for (int ni = 0; ni < 3; ++ni)
            acc[mi][ni] = (f32x4){0.f, 0.f, 0.f, 0.f};

    const int mat  = t & 1;        // 0 = k, 1 = v
    const int lrow = t >> 1;       // 0..127
    const int tile = lrow >> 5, l_in = lrow & 31;
    const __hip_bfloat16* src = qkv + 384 + mat * 384 + h * 48;
    __hip_bfloat16* dstT = (mat ? &vT[0][0][0] : &kT[0][0][0]) + ((size_t)tile * 48 * 40 + l_in);

    for (int it = 0; it < 8; ++it) {
        const int l0 = lbase + it * 128;
        const __hip_bfloat16* p = src + (size_t)(b * 4096 + l0 + lrow) * 1152;
        __hip_bfloat16 row[48];
        #pragma unroll
        for (int j = 0; j < 6; ++j) {
            uint4 v = *(const uint4*)(p + j * 8);
            __builtin_memcpy(&row[j * 8], &v, 16);
        }
        #pragma unroll
        for (int d = 0; d < 48; ++d)
            dstT[d * 40] = row[d];
        __syncthreads();

        bf16x8 af[3], bfr[3];
        #pragma unroll
        for (int mi = 0; mi < 3; ++mi)
            af[mi] = *(const bf16x8*)&kT[w][mi * 16 + r16][quad * 8];
        #pragma unroll
        for (int ni = 0; ni < 3; ++ni)
            bfr[ni] = *(const bf16x8*)&vT[w][ni * 16 + r16][quad * 8];
        #pragma unroll
        for (int mi = 0; mi < 3; ++mi)
            #pragma unroll
            for (int ni = 0; ni < 3; ++ni)
                acc[mi][ni] = __builtin_amdgcn_mfma_f32_16x16x32_bf16(af[mi], bfr[ni], acc[mi][ni], 0, 0, 0);
        __syncthreads();
    }

    #pragma unroll
    for (int mi = 0; mi < 3; ++mi)
        #pragma unroll
        for (int ni = 0; ni < 3; ++ni)
            #pragma unroll
            for (int reg = 0; reg < 4; ++reg)
                red[w][mi * 16 + quad * 4 + reg][ni * 16 + r16] = acc[mi][ni][reg];
    __syncthreads();

    float* Gb = G + (size_t)bh * 2304;
    for (int cell = t; cell < 2304; cell += 256) {
        int row = cell / 48, col = cell % 48;
        float s = red[0][row][col] + red[1][row][col] + red[2][row][col] + red[3][row][col];
        atomicAdd(&Gb[cell], s);
    }
}

// ---------------------------------------------------------------------------
// attn = G * invnorm_k[d] * temp[h] -> fp32 out;  attn2 = attn * invnorm_q[d]
// ---------------------------------------------------------------------------
__global__ void scale_attn_kernel(
    const float* __restrict__ G, const float* __restrict__ invn,
    const float* __restrict__ temp,
    float* __restrict__ attn_out, float* __restrict__ attn2)
{
    int bh = blockIdx.x; int b = bh >> 3; int h = bh & 7;
    float tf = temp[h];
    int t = threadIdx.x;
    for (int e = t; e < 2304; e += 256) {
        int dk = e / 48;
        float ink = invn[b * 768 + 384 + h * 48 + dk];
        float inq = invn[b * 768 + h * 48 + dk];
        float av  = G[(size_t)bh * 2304 + e] * ink * tf;
        attn_out[(size_t)bh * 2304 + e] = av;
        attn2[(size_t)bh * 2304 + e]    = av * inq;
    }
}

// ---------------------------------------------------------------------------
// y[b,l,h*48+e] = sum_d q[b,h,l,d]*attn2[d,e] + lepe(v)  — MFMA version.
// Grid (32, 64): block = 128 L-rows (2 image rows) x 48 cols for one (b,h).
// q@attn2 via 16x16x32 MFMA, K=48 zero-padded to 64 (2 k-steps, 12 MFMA/wave).
// LePE: v rows yi0-1..yi0+2 staged in LDS; conv phase is channel-vectorized
// (ds_read_b128 = 8 channels/tap). qs+a2s LDS region aliased as ys (matmul
// round-trip) — barrier-separated.
// ---------------------------------------------------------------------------
__global__ __launch_bounds__(256) void qattn_lepe_mfma(
    const __hip_bfloat16* __restrict__ qkv, const float* __restrict__ attn2,
    const float* __restrict__ conv_w, const float* __restrict__ conv_b,
    __hip_bfloat16* __restrict__ y)
{
    __shared__ __attribute__((aligned(16))) char smem[26624];
    __hip_bfloat16 (*qs)[72]  = (__hip_bfloat16 (*)[72])smem;            // [128][72]
    __hip_bfloat16 (*a2s)[72] = (__hip_bfloat16 (*)[72])(smem + 18432);  // [48][72]
    float (*ys)[52]           = (float (*)[52])smem;                     // [128][52]
    __shared__ __hip_bfloat16 vs[4][64][48];   // 24576 B
    __shared__ float cwT[9][48];
    __shared__ float cb[48];

    const int bh = blockIdx.y; const int b = bh >> 3; const int h = bh & 7;
    const int yi0 = blockIdx.x * 2;            // first image row of this block
    const int l0  = yi0 * 64;                  // first L index
    const int t = threadIdx.x;
    const int w = t >> 6, lane = t & 63;
    const int r16 = lane & 15, quad = lane >> 4;

    // ---- stage q tile (128 x 48, k-pad 48..63 = 0) ----
    const __hip_bfloat16* qbase = qkv + (size_t)(b * 4096 + l0) * 1152 + h * 48;
    #pragma unroll
    for (int i = 0; i < 3; ++i) {
        int chunk = t + i * 256;               // 768 chunks
        int row = chunk / 6, cg = chunk % 6;
        *(bf16x8*)&qs[row][cg * 8] = load8(qbase + (size_t)row * 1152 + cg * 8);
    }
    *(bf16x8*)&qs[t >> 1][48 + (t & 1) * 8] = (bf16x8)0;   // zero pad k 48..63

    // ---- stage attn2 transposed: a2s[e][d] (bf16, k-pad 48..63 = 0) ----
    const float* a2g = attn2 + (size_t)bh * 2304;
    for (int i = t; i < 3072; i += 256) {
        int e = i >> 6, dd = i & 63;
        float val = (dd < 48) ? a2g[dd * 48 + e] : 0.f;
        a2s[e][dd] = __float2bfloat16(val);
    }

    // ---- stage v image rows yi0-1 .. yi0+2 (zeros outside image) ----
    const __hip_bfloat16* vbase = qkv + (size_t)b * 4096 * 1152 + 768 + h * 48;
    #pragma unroll
    for (int i = 0; i < 6; ++i) {
        int chunk = t + i * 256;               // 1536 chunks
        int r = chunk / 384, rem = chunk % 384;
        int xx = rem / 6, cg = rem % 6;
        int yy = yi0 - 1 + r;
        bf16x8 v = (yy >= 0 && yy < 64)
            ? load8(vbase + (size_t)(yy * 64 + xx) * 1152 + cg * 8)
            : (bf16x8)0;
        *(bf16x8*)&vs[r][xx][cg * 8] = v;
    }

    // ---- conv weights (transposed) + bias ----
    for (int i = t; i < 432; i += 256)
        cwT[i / 48][i % 48] = conv_w[(h * 48 + (i % 48)) * 9 + (i / 48)];
    if (t < 48) cb[t] = conv_b[h * 48 + t];
    __syncthreads();

    // ---- MFMA: wave w computes rows w*32..w*32+31 ----
    f32x4 acc[2][3];
    #pragma unroll
    for (int mi = 0; mi < 2; ++mi)
        #pragma unroll
        for (int ni = 0; ni < 3; ++ni)
            acc[mi][ni] = (f32x4){0.f, 0.f, 0.f, 0.f};
    #pragma unroll
    for (int ks = 0; ks < 2; ++ks) {
        int kb = ks * 32 + quad * 8;
        bf16x8 af[2], bfr[3];
        #pragma unroll
        for (int mi = 0; mi < 2; ++mi)
            af[mi] = *(const bf16x8*)&qs[w * 32 + mi * 16 + r16][kb];
        #pragma unroll
        for (int ni = 0; ni < 3; ++ni)
            bfr[ni] = *(const bf16x8*)&a2s[ni * 16 + r16][kb];
        #pragma unroll
        for (int mi = 0; mi < 2; ++mi)
            #pragma unroll
            for (int ni = 0; ni < 3; ++ni)
                acc[mi][ni] = __builtin_amdgcn_mfma_f32_16x16x32_bf16(af[mi], bfr[ni], acc[mi][ni], 0, 0, 0);
    }
    __syncthreads();   // all waves done reading qs/a2s — safe to alias as ys

    // ---- write matmul result to ys (C/D layout: col=lane&15, row=quad*4+reg)
    #pragma unroll
    for (int mi = 0; mi < 2; ++mi)
        #pragma unroll
        for (int ni = 0; ni < 3; ++ni)
            #pragma unroll
            for (int reg = 0; reg < 4; ++reg)
                ys[w * 32 + mi * 16 + quad * 4 + reg][ni * 16 + r16] = acc[mi][ni][reg];
    __syncthreads();

    // ---- conv + bias + store (channel-vectorized, 8 ch per group) ----
    __hip_bfloat16* ybase = y + (size_t)(b * 4096 + l0) * 384 + h * 48;
    #pragma unroll
    for (int i = 0; i < 3; ++i) {
        int g = t + i * 256;                   // 768 groups
        int l_in = g / 6, cg = g % 6, e0 = cg * 8;
        int xi = l_in & 63, vr0 = l_in >> 6;   // local image col / base v-row
        float o[8];
        #pragma unroll
        for (int j = 0; j < 8; ++j) o[j] = ys[l_in][e0 + j] + cb[e0 + j];
        #pragma unroll
        for (int dy = 0; dy < 3; ++dy) {
            #pragma unroll
            for (int dx = 0; dx < 3; ++dx) {
                int xx = xi + dx - 1;
                if (xx < 0 || xx > 63) continue;
                bf16x8 vv = *(const bf16x8*)&vs[vr0 + dy][xx][e0];
                const float* cwp = &cwT[dy * 3 + dx][e0];
                #pragma unroll
                for (int j = 0; j < 8; ++j) o[j] += b2f(vv[j]) * cwp[j];
            }
        }
        __hip_bfloat16 ob[8];
        #pragma unroll
        for (int j = 0; j < 8; ++j) ob[j] = __float2bfloat16(o[j]);
        uint4 pk; __builtin_memcpy(&pk, ob, 16);
        *(uint4*)(ybase + (size_t)l_in * 384 + e0) = pk;
    }
}

// ---------------------------------------------------------------------------
extern "C" void kernel_launch(void* const* d_in, const int* in_sizes, int n_in,
                              void* d_out, int out_size, void* d_ws, size_t ws_size,
                              hipStream_t stream)
{
    const float* x      = (const float*)d_in[0];
    const float* qkv_w  = (const float*)d_in[1];
    const float* qkv_b  = (const float*)d_in[2];
    const float* proj_w = (const float*)d_in[3];
    const float* proj_b = (const float*)d_in[4];
    const float* temp   = (const float*)d_in[5];
    const float* conv_w = (const float*)d_in[6];
    const float* conv_b = (const float*)d_in[7];

    char* ws = (char*)d_ws;
    __hip_bfloat16* qkv = (__hip_bfloat16*)(ws);                 // 75,497,472 B
    __hip_bfloat16* yb  = (__hip_bfloat16*)(ws + 75497472);      // 25,165,824 B
    float* sumsq = (float*)(ws + 100663296);                     // 24,576 B
    float* G     = (float*)(ws + 100687872);                     // 589,824 B
    float* invn  = (float*)(ws + 101277696);                     // 24,576 B
    float* attn2 = (float*)(ws + 101302272);                     // 589,824 B

    float* out      = (float*)d_out;
    float* attn_out = out + 12582912;

    // zero the atomic accumulators (sumsq + G are contiguous)
    (void)hipMemsetAsync(ws + 100663296, 0, 614400, stream);

    // 1) qkv = x @ qkv_w^T + qkv_b   (fp32 in -> bf16 out)
    gemm_nt_bias<float, __hip_bfloat16><<<dim3(18, 256), 256, 0, stream>>>(
        x, qkv_w, qkv_b, qkv, 32768, 1152, 384);
    // 2) column sumsq of q,k over L
    colsumsq_kernel<<<dim3(64, 8), 256, 0, stream>>>(qkv, sumsq);
    invnorm_kernel<<<24, 256, 0, stream>>>(sumsq, invn);
    // 3) G = k^T v  (MFMA)
    ktv_mfma_kernel<<<dim3(4, 64), 256, 0, stream>>>(qkv, G);
    // 4) attn (fp32 out) + attn2 (fp32, q-norm folded)
    scale_attn_kernel<<<64, 256, 0, stream>>>(G, invn, temp, attn_out, attn2);
    // 5) y = q @ attn2 + lepe   (MFMA, bf16 out)
    qattn_lepe_mfma<<<dim3(32, 64), 256, 0, stream>>>(qkv, attn2, conv_w, conv_b, yb);
    // 6) out = y @ proj_w^T + proj_b   (bf16 A -> fp32 out)
    gemm_nt_bias<__hip_bfloat16, float><<<dim3(6, 256), 256, 0, stream>>>(
        yb, proj_w, proj_b, out, 32768, 384, 384);
}

// Round 6
// 265.100 us; speedup vs baseline: 2.1630x; 1.0770x over previous
//
#include <hip/hip_runtime.h>
#include <hip/hip_bf16.h>

// B=8, L=4096, C=384, h=8, d=48, H=W=64
// Inputs/outputs fp32 (per reference). Internals: x/weights pre-converted to
// bf16 (ws), qkv/y bf16 (ws), sumsq/G/invnorm/attn2 fp32 (ws).

typedef __bf16 bf16x8 __attribute__((ext_vector_type(8)));
typedef float f32x4 __attribute__((ext_vector_type(4)));

__device__ inline __bf16 f2b(float f) {
    __hip_bfloat16 h = __float2bfloat16(f);
    __bf16 r; __builtin_memcpy(&r, &h, 2); return r;
}
__device__ inline float b2f(__hip_bfloat16 h) { return __bfloat162float(h); }
__device__ inline float b2f(__bf16 v) {
    __hip_bfloat16 h; __builtin_memcpy(&h, &v, 2); return __bfloat162float(h);
}

__device__ inline bf16x8 load8(const __hip_bfloat16* p) {
    uint4 v = *(const uint4*)p;
    bf16x8 r; __builtin_memcpy(&r, &v, 16); return r;
}
__device__ inline bf16x8 load8(const float* p) {
    float4 a = *(const float4*)p;
    float4 b = *(const float4*)(p + 4);
    bf16x8 r;
    r[0] = f2b(a.x); r[1] = f2b(a.y); r[2] = f2b(a.z); r[3] = f2b(a.w);
    r[4] = f2b(b.x); r[5] = f2b(b.y); r[6] = f2b(b.z); r[7] = f2b(b.w);
    return r;
}

__device__ inline void storef(float* p, float v) { *p = v; }
__device__ inline void storef(__hip_bfloat16* p, float v) { *p = __float2bfloat16(v); }

// async 16B global -> LDS (wave-uniform base + lane*16 dest required)
__device__ inline void gl_lds16(const __hip_bfloat16* g, __hip_bfloat16* l) {
    __builtin_amdgcn_global_load_lds(
        (const __attribute__((address_space(1))) void*)g,
        (__attribute__((address_space(3))) void*)l,
        16, 0, 0);
}

// ---------------------------------------------------------------------------
// fp32 -> bf16 conversion: x (6144 blocks), qkv_w (216), proj_w (72)
// ---------------------------------------------------------------------------
__global__ __launch_bounds__(256) void cvt_kernel(
    const float* __restrict__ x,  __hip_bfloat16* __restrict__ xb,
    const float* __restrict__ qw, __hip_bfloat16* __restrict__ qwb,
    const float* __restrict__ pw, __hip_bfloat16* __restrict__ pwb)
{
    int blk = blockIdx.x;
    const float* src; __hip_bfloat16* dst; int base;
    if (blk < 6144)      { src = x;  dst = xb;  base = blk; }
    else if (blk < 6360) { src = qw; dst = qwb; base = blk - 6144; }
    else                 { src = pw; dst = pwb; base = blk - 6360; }
    int i = base * 256 + threadIdx.x;
    bf16x8 v = load8(src + (size_t)i * 8);
    *(bf16x8*)(dst + (size_t)i * 8) = v;
}

// ---------------------------------------------------------------------------
// GEMM (m97 structure): C[M,N] = A[M,K] @ Bw[N,K]^T + bias[N], bf16 in.
// Block tile 128x128, waves 2x2 (each 64x64 = 4x4 MFMA 16x16x32), BK=32.
// Staging via global_load_lds width-16 into unpadded [128][32] LDS.
// ---------------------------------------------------------------------------
template <typename TO>
__global__ __launch_bounds__(256) void gemm_bf16_nt(
    const __hip_bfloat16* __restrict__ A,
    const __hip_bfloat16* __restrict__ Bw,
    const float* __restrict__ bias,
    TO* __restrict__ C,
    int M, int N, int K)
{
    __shared__ __hip_bfloat16 As[128 * 32];
    __shared__ __hip_bfloat16 Bs[128 * 32];
    const int t = threadIdx.x;
    const int w = t >> 6, lane = t & 63;
    const int r16 = lane & 15, quad = lane >> 4;
    const int m0 = blockIdx.y * 128, n0 = blockIdx.x * 128;
    const int wm = w >> 1, wn = w & 1;
    const int srow = lane >> 2;          // 0..15 within a 16-row chunk
    const int scol = (lane & 3) * 8;     // element col within 32

    f32x4 acc[4][4];
    #pragma unroll
    for (int mi = 0; mi < 4; ++mi)
        #pragma unroll
        for (int ni = 0; ni < 4; ++ni)
            acc[mi][ni] = (f32x4){0.f, 0.f, 0.f, 0.f};

    for (int k0 = 0; k0 < K; k0 += 32) {
        // wave w stages A rows [w*32, w*32+32) and B rows likewise; each
        // 16-row chunk is 1KB = 64 lanes x 16B, lane-contiguous in LDS.
        #pragma unroll
        for (int p = 0; p < 2; ++p) {
            int row = w * 32 + p * 16 + srow;
            gl_lds16(A  + (size_t)(m0 + row) * K + k0 + scol, &As[row * 32 + scol]);
            gl_lds16(Bw + (size_t)(n0 + row) * K + k0 + scol, &Bs[row * 32 + scol]);
        }
        __syncthreads();   // drains vmcnt (incl. global_load_lds) + lgkm
        bf16x8 af[4], bfr[4];
        #pragma unroll
        for (int mi = 0; mi < 4; ++mi)
            af[mi] = *(const bf16x8*)&As[(wm * 64 + mi * 16 + r16) * 32 + quad * 8];
        #pragma unroll
        for (int ni = 0; ni < 4; ++ni)
            bfr[ni] = *(const bf16x8*)&Bs[(wn * 64 + ni * 16 + r16) * 32 + quad * 8];
        #pragma unroll
        for (int mi = 0; mi < 4; ++mi)
            #pragma unroll
            for (int ni = 0; ni < 4; ++ni)
                acc[mi][ni] = __builtin_amdgcn_mfma_f32_16x16x32_bf16(af[mi], bfr[ni], acc[mi][ni], 0, 0, 0);
        __syncthreads();
    }

    #pragma unroll
    for (int ni = 0; ni < 4; ++ni) {
        int col = n0 + wn * 64 + ni * 16 + r16;
        float bv = bias[col];
        #pragma unroll
        for (int mi = 0; mi < 4; ++mi) {
            #pragma unroll
            for (int reg = 0; reg < 4; ++reg) {
                int row = m0 + wm * 64 + mi * 16 + quad * 4 + reg;
                storef(&C[(size_t)row * N + col], acc[mi][ni][reg] + bv);
            }
        }
    }
}

// ---------------------------------------------------------------------------
// Column sum-of-squares over L for q,k (cols 0..767 of qkv). Atomic partials.
// ---------------------------------------------------------------------------
__global__ __launch_bounds__(256) void colsumsq_kernel(
    const __hip_bfloat16* __restrict__ qkv, float* __restrict__ sumsq)
{
    int b  = blockIdx.y;
    int l0 = blockIdx.x * 64;
    int t  = threadIdx.x;
    const __hip_bfloat16* base = qkv + (size_t)(b * 4096 + l0) * 1152;
    #pragma unroll
    for (int p = 0; p < 3; ++p) {
        int c = p * 256 + t;
        float acc = 0.f;
        for (int r = 0; r < 64; ++r) {
            float v = b2f(base[(size_t)r * 1152 + c]);
            acc += v * v;
        }
        atomicAdd(&sumsq[b * 768 + c], acc);
    }
}

__global__ void invnorm_kernel(const float* __restrict__ sumsq, float* __restrict__ invn)
{
    int i = blockIdx.x * 256 + threadIdx.x;
    if (i < 6144) invn[i] = 1.f / fmaxf(sqrtf(sumsq[i]), 1e-12f);
}

// ---------------------------------------------------------------------------
// G[bh] = k^T v  via MFMA.  Grid (4, 64): each block covers 1024 of L for one
// (b,h). 4 waves on disjoint 32-l chunks; k,v tiles staged TRANSPOSED in LDS.
// ---------------------------------------------------------------------------
__global__ __launch_bounds__(256) void ktv_mfma_kernel(
    const __hip_bfloat16* __restrict__ qkv, float* __restrict__ G)
{
    __shared__ __hip_bfloat16 kT[4][48][40];
    __shared__ __hip_bfloat16 vT[4][48][40];
    __shared__ float red[4][48][49];   // +1 pad: quad rows land on distinct banks

    const int bh = blockIdx.y; const int b = bh >> 3; const int h = bh & 7;
    const int lbase = blockIdx.x * 1024;
    const int t = threadIdx.x;
    const int w = t >> 6, lane = t & 63;
    const int r16 = lane & 15, quad = lane >> 4;

    f32x4 acc[3][3];
    #pragma unroll
    for (int mi = 0; mi < 3; ++mi)
        #pragma unroll
        for (int ni = 0; ni < 3; ++ni)
            acc[mi][ni] = (f32x4){0.f, 0.f, 0.f, 0.f};

    const int mat  = t & 1;        // 0 = k, 1 = v
    const int lrow = t >> 1;       // 0..127
    const int tile = lrow >> 5, l_in = lrow & 31;
    const __hip_bfloat16* src = qkv + 384 + mat * 384 + h * 48;
    __hip_bfloat16* dstT = (mat ? &vT[0][0][0] : &kT[0][0][0]) + ((size_t)tile * 48 * 40 + l_in);

    for (int it = 0; it < 8; ++it) {
        const int l0 = lbase + it * 128;
        const __hip_bfloat16* p = src + (size_t)(b * 4096 + l0 + lrow) * 1152;
        __hip_bfloat16 row[48];
        #pragma unroll
        for (int j = 0; j < 6; ++j) {
            uint4 v = *(const uint4*)(p + j * 8);
            __builtin_memcpy(&row[j * 8], &v, 16);
        }
        #pragma unroll
        for (int d = 0; d < 48; ++d)
            dstT[d * 40] = row[d];
        __syncthreads();

        bf16x8 af[3], bfr[3];
        #pragma unroll
        for (int mi = 0; mi < 3; ++mi)
            af[mi] = *(const bf16x8*)&kT[w][mi * 16 + r16][quad * 8];
        #pragma unroll
        for (int ni = 0; ni < 3; ++ni)
            bfr[ni] = *(const bf16x8*)&vT[w][ni * 16 + r16][quad * 8];
        #pragma unroll
        for (int mi = 0; mi < 3; ++mi)
            #pragma unroll
            for (int ni = 0; ni < 3; ++ni)
                acc[mi][ni] = __builtin_amdgcn_mfma_f32_16x16x32_bf16(af[mi], bfr[ni], acc[mi][ni], 0, 0, 0);
        __syncthreads();
    }

    #pragma unroll
    for (int mi = 0; mi < 3; ++mi)
        #pragma unroll
        for (int ni = 0; ni < 3; ++ni)
            #pragma unroll
            for (int reg = 0; reg < 4; ++reg)
                red[w][mi * 16 + quad * 4 + reg][ni * 16 + r16] = acc[mi][ni][reg];
    __syncthreads();

    float* Gb = G + (size_t)bh * 2304;
    for (int cell = t; cell < 2304; cell += 256) {
        int row = cell / 48, col = cell % 48;
        float s = red[0][row][col] + red[1][row][col] + red[2][row][col] + red[3][row][col];
        atomicAdd(&Gb[cell], s);
    }
}

// ---------------------------------------------------------------------------
// attn = G * invnorm_k[d] * temp[h] -> fp32 out;  attn2 = attn * invnorm_q[d]
// ---------------------------------------------------------------------------
__global__ void scale_attn_kernel(
    const float* __restrict__ G, const float* __restrict__ invn,
    const float* __restrict__ temp,
    float* __restrict__ attn_out, float* __restrict__ attn2)
{
    int bh = blockIdx.x; int b = bh >> 3; int h = bh & 7;
    float tf = temp[h];
    int t = threadIdx.x;
    for (int e = t; e < 2304; e += 256) {
        int dk = e / 48;
        float ink = invn[b * 768 + 384 + h * 48 + dk];
        float inq = invn[b * 768 + h * 48 + dk];
        float av  = G[(size_t)bh * 2304 + e] * ink * tf;
        attn_out[(size_t)bh * 2304 + e] = av;
        attn2[(size_t)bh * 2304 + e]    = av * inq;
    }
}

// ---------------------------------------------------------------------------
// y[b,l,h*48+e] = sum_d q[b,h,l,d]*attn2[d,e] + lepe(v)  — MFMA version.
// ---------------------------------------------------------------------------
__global__ __launch_bounds__(256) void qattn_lepe_mfma(
    const __hip_bfloat16* __restrict__ qkv, const float* __restrict__ attn2,
    const float* __restrict__ conv_w, const float* __restrict__ conv_b,
    __hip_bfloat16* __restrict__ y)
{
    __shared__ __attribute__((aligned(16))) char smem[26624];
    __hip_bfloat16 (*qs)[72]  = (__hip_bfloat16 (*)[72])smem;            // [128][72]
    __hip_bfloat16 (*a2s)[72] = (__hip_bfloat16 (*)[72])(smem + 18432);  // [48][72]
    float (*ys)[52]           = (float (*)[52])smem;                     // [128][52]
    __shared__ __hip_bfloat16 vs[4][64][48];   // 24576 B
    __shared__ float cwT[9][48];
    __shared__ float cb[48];

    const int bh = blockIdx.y; const int b = bh >> 3; const int h = bh & 7;
    const int yi0 = blockIdx.x * 2;            // first image row of this block
    const int l0  = yi0 * 64;                  // first L index
    const int t = threadIdx.x;
    const int w = t >> 6, lane = t & 63;
    const int r16 = lane & 15, quad = lane >> 4;

    // ---- stage q tile (128 x 48, k-pad 48..63 = 0) ----
    const __hip_bfloat16* qbase = qkv + (size_t)(b * 4096 + l0) * 1152 + h * 48;
    #pragma unroll
    for (int i = 0; i < 3; ++i) {
        int chunk = t + i * 256;               // 768 chunks
        int row = chunk / 6, cg = chunk % 6;
        *(bf16x8*)&qs[row][cg * 8] = load8(qbase + (size_t)row * 1152 + cg * 8);
    }
    *(bf16x8*)&qs[t >> 1][48 + (t & 1) * 8] = (bf16x8)0;   // zero pad k 48..63

    // ---- stage attn2 transposed: a2s[e][d] (bf16, k-pad 48..63 = 0) ----
    const float* a2g = attn2 + (size_t)bh * 2304;
    for (int i = t; i < 3072; i += 256) {
        int e = i >> 6, dd = i & 63;
        float val = (dd < 48) ? a2g[dd * 48 + e] : 0.f;
        a2s[e][dd] = __float2bfloat16(val);
    }

    // ---- stage v image rows yi0-1 .. yi0+2 (zeros outside image) ----
    const __hip_bfloat16* vbase = qkv + (size_t)b * 4096 * 1152 + 768 + h * 48;
    #pragma unroll
    for (int i = 0; i < 6; ++i) {
        int chunk = t + i * 256;               // 1536 chunks
        int r = chunk / 384, rem = chunk % 384;
        int xx = rem / 6, cg = rem % 6;
        int yy = yi0 - 1 + r;
        bf16x8 v = (yy >= 0 && yy < 64)
            ? load8(vbase + (size_t)(yy * 64 + xx) * 1152 + cg * 8)
            : (bf16x8)0;
        *(bf16x8*)&vs[r][xx][cg * 8] = v;
    }

    // ---- conv weights (transposed) + bias ----
    for (int i = t; i < 432; i += 256)
        cwT[i / 48][i % 48] = conv_w[(h * 48 + (i % 48)) * 9 + (i / 48)];
    if (t < 48) cb[t] = conv_b[h * 48 + t];
    __syncthreads();

    // ---- MFMA: wave w computes rows w*32..w*32+31 ----
    f32x4 acc[2][3];
    #pragma unroll
    for (int mi = 0; mi < 2; ++mi)
        #pragma unroll
        for (int ni = 0; ni < 3; ++ni)
            acc[mi][ni] = (f32x4){0.f, 0.f, 0.f, 0.f};
    #pragma unroll
    for (int ks = 0; ks < 2; ++ks) {
        int kb = ks * 32 + quad * 8;
        bf16x8 af[2], bfr[3];
        #pragma unroll
        for (int mi = 0; mi < 2; ++mi)
            af[mi] = *(const bf16x8*)&qs[w * 32 + mi * 16 + r16][kb];
        #pragma unroll
        for (int ni = 0; ni < 3; ++ni)
            bfr[ni] = *(const bf16x8*)&a2s[ni * 16 + r16][kb];
        #pragma unroll
        for (int mi = 0; mi < 2; ++mi)
            #pragma unroll
            for (int ni = 0; ni < 3; ++ni)
                acc[mi][ni] = __builtin_amdgcn_mfma_f32_16x16x32_bf16(af[mi], bfr[ni], acc[mi][ni], 0, 0, 0);
    }
    __syncthreads();   // all waves done reading qs/a2s — safe to alias as ys

    // ---- write matmul result to ys (C/D layout: col=lane&15, row=quad*4+reg)
    #pragma unroll
    for (int mi = 0; mi < 2; ++mi)
        #pragma unroll
        for (int ni = 0; ni < 3; ++ni)
            #pragma unroll
            for (int reg = 0; reg < 4; ++reg)
                ys[w * 32 + mi * 16 + quad * 4 + reg][ni * 16 + r16] = acc[mi][ni][reg];
    __syncthreads();

    // ---- conv + bias + store (channel-vectorized, 8 ch per group) ----
    __hip_bfloat16* ybase = y + (size_t)(b * 4096 + l0) * 384 + h * 48;
    #pragma unroll
    for (int i = 0; i < 3; ++i) {
        int g = t + i * 256;                   // 768 groups
        int l_in = g / 6, cg = g % 6, e0 = cg * 8;
        int xi = l_in & 63, vr0 = l_in >> 6;   // local image col / base v-row
        float o[8];
        #pragma unroll
        for (int j = 0; j < 8; ++j) o[j] = ys[l_in][e0 + j] + cb[e0 + j];
        #pragma unroll
        for (int dy = 0; dy < 3; ++dy) {
            #pragma unroll
            for (int dx = 0; dx < 3; ++dx) {
                int xx = xi + dx - 1;
                if (xx < 0 || xx > 63) continue;
                bf16x8 vv = *(const bf16x8*)&vs[vr0 + dy][xx][e0];
                const float* cwp = &cwT[dy * 3 + dx][e0];
                #pragma unroll
                for (int j = 0; j < 8; ++j) o[j] += b2f(vv[j]) * cwp[j];
            }
        }
        __hip_bfloat16 ob[8];
        #pragma unroll
        for (int j = 0; j < 8; ++j) ob[j] = __float2bfloat16(o[j]);
        uint4 pk; __builtin_memcpy(&pk, ob, 16);
        *(uint4*)(ybase + (size_t)l_in * 384 + e0) = pk;
    }
}

// ---------------------------------------------------------------------------
extern "C" void kernel_launch(void* const* d_in, const int* in_sizes, int n_in,
                              void* d_out, int out_size, void* d_ws, size_t ws_size,
                              hipStream_t stream)
{
    const float* x      = (const float*)d_in[0];
    const float* qkv_w  = (const float*)d_in[1];
    const float* qkv_b  = (const float*)d_in[2];
    const float* proj_w = (const float*)d_in[3];
    const float* proj_b = (const float*)d_in[4];
    const float* temp   = (const float*)d_in[5];
    const float* conv_w = (const float*)d_in[6];
    const float* conv_b = (const float*)d_in[7];

    char* ws = (char*)d_ws;
    __hip_bfloat16* qkv = (__hip_bfloat16*)(ws);                 // 75,497,472 B
    __hip_bfloat16* yb  = (__hip_bfloat16*)(ws + 75497472);      // 25,165,824 B
    float* sumsq = (float*)(ws + 100663296);                     // 24,576 B
    float* G     = (float*)(ws + 100687872);                     // 589,824 B
    float* invn  = (float*)(ws + 101277696);                     // 24,576 B
    float* attn2 = (float*)(ws + 101302272);                     // 589,824 B
    // x_bf16 aliases yb (dead until qattn_lepe); weight bf16 copies appended
    __hip_bfloat16* x_bf16  = yb;
    __hip_bfloat16* qkv_wb  = (__hip_bfloat16*)(ws + 101892096); // 884,736 B
    __hip_bfloat16* proj_wb = (__hip_bfloat16*)(ws + 102776832); // 294,912 B

    float* out      = (float*)d_out;
    float* attn_out = out + 12582912;

    // zero the atomic accumulators (sumsq + G are contiguous)
    (void)hipMemsetAsync(ws + 100663296, 0, 614400, stream);

    // 0) convert x, qkv_w, proj_w to bf16
    cvt_kernel<<<6432, 256, 0, stream>>>(x, x_bf16, qkv_w, qkv_wb, proj_w, proj_wb);
    // 1) qkv = x @ qkv_w^T + qkv_b   (bf16 -> bf16)
    gemm_bf16_nt<__hip_bfloat16><<<dim3(9, 256), 256, 0, stream>>>(
        x_bf16, qkv_wb, qkv_b, qkv, 32768, 1152, 384);
    // 2) column sumsq of q,k over L
    colsumsq_kernel<<<dim3(64, 8), 256, 0, stream>>>(qkv, sumsq);
    invnorm_kernel<<<24, 256, 0, stream>>>(sumsq, invn);
    // 3) G = k^T v  (MFMA)
    ktv_mfma_kernel<<<dim3(4, 64), 256, 0, stream>>>(qkv, G);
    // 4) attn (fp32 out) + attn2 (fp32, q-norm folded)
    scale_attn_kernel<<<64, 256, 0, stream>>>(G, invn, temp, attn_out, attn2);
    // 5) y = q @ attn2 + lepe   (MFMA, bf16 out — overwrites x_bf16 alias)
    qattn_lepe_mfma<<<dim3(32, 64), 256, 0, stream>>>(qkv, attn2, conv_w, conv_b, yb);
    // 6) out = y @ proj_w^T + proj_b   (bf16 -> fp32)
    gemm_bf16_nt<float><<<dim3(3, 256), 256, 0, stream>>>(
        yb, proj_wb, proj_b, out, 32768, 384, 384);
}

// Round 7
// 256.814 us; speedup vs baseline: 2.2328x; 1.0323x over previous
//
#include <hip/hip_runtime.h>
#include <hip/hip_bf16.h>

// B=8, L=4096, C=384, h=8, d=48, H=W=64
// Inputs/outputs fp32 (per reference). Internals: x/weights pre-converted to
// bf16 (ws), qkv/y bf16 (ws), sumsq/G/invnorm/attn2 fp32 (ws).

typedef __bf16 bf16x8 __attribute__((ext_vector_type(8)));
typedef float f32x4 __attribute__((ext_vector_type(4)));

__device__ inline __bf16 f2b(float f) {
    __hip_bfloat16 h = __float2bfloat16(f);
    __bf16 r; __builtin_memcpy(&r, &h, 2); return r;
}
__device__ inline float b2f(__hip_bfloat16 h) { return __bfloat162float(h); }
__device__ inline float b2f(__bf16 v) {
    __hip_bfloat16 h; __builtin_memcpy(&h, &v, 2); return __bfloat162float(h);
}

__device__ inline bf16x8 load8(const __hip_bfloat16* p) {
    uint4 v = *(const uint4*)p;
    bf16x8 r; __builtin_memcpy(&r, &v, 16); return r;
}
__device__ inline bf16x8 load8(const float* p) {
    float4 a = *(const float4*)p;
    float4 b = *(const float4*)(p + 4);
    bf16x8 r;
    r[0] = f2b(a.x); r[1] = f2b(a.y); r[2] = f2b(a.z); r[3] = f2b(a.w);
    r[4] = f2b(b.x); r[5] = f2b(b.y); r[6] = f2b(b.z); r[7] = f2b(b.w);
    return r;
}

__device__ inline void storef(float* p, float v) { *p = v; }
__device__ inline void storef(__hip_bfloat16* p, float v) { *p = __float2bfloat16(v); }

// async 16B global -> LDS (wave-uniform base + lane*16 dest required)
__device__ inline void gl_lds16(const __hip_bfloat16* g, __hip_bfloat16* l) {
    __builtin_amdgcn_global_load_lds(
        (const __attribute__((address_space(1))) void*)g,
        (__attribute__((address_space(3))) void*)l,
        16, 0, 0);
}

// ---------------------------------------------------------------------------
// fp32 -> bf16 conversion: x (6144 blocks), qkv_w (216), proj_w (72)
// ---------------------------------------------------------------------------
__global__ __launch_bounds__(256) void cvt_kernel(
    const float* __restrict__ x,  __hip_bfloat16* __restrict__ xb,
    const float* __restrict__ qw, __hip_bfloat16* __restrict__ qwb,
    const float* __restrict__ pw, __hip_bfloat16* __restrict__ pwb)
{
    int blk = blockIdx.x;
    const float* src; __hip_bfloat16* dst; int base;
    if (blk < 6144)      { src = x;  dst = xb;  base = blk; }
    else if (blk < 6360) { src = qw; dst = qwb; base = blk - 6144; }
    else                 { src = pw; dst = pwb; base = blk - 6360; }
    int i = base * 256 + threadIdx.x;
    bf16x8 v = load8(src + (size_t)i * 8);
    *(bf16x8*)(dst + (size_t)i * 8) = v;
}

// ---------------------------------------------------------------------------
// GEMM (m97 structure): C[M,N] = A[M,K] @ Bw[N,K]^T + bias[N], bf16 in.
// Block tile 128x128, waves 2x2 (each 64x64 = 4x4 MFMA 16x16x32), BK=32.
// Staging via global_load_lds width-16 into unpadded [128][32] LDS.
// 1-D grid with XCD-aware swizzle: all NXT column-tiles of one row-tile run
// consecutively on ONE XCD (row-tile <-> XCD partition -> A fetched ~once).
// Optional fused column sum-of-squares (cols < 768) into sumsq via atomics.
// ---------------------------------------------------------------------------
template <typename TO>
__global__ __launch_bounds__(256) void gemm_bf16_nt(
    const __hip_bfloat16* __restrict__ A,
    const __hip_bfloat16* __restrict__ Bw,
    const float* __restrict__ bias,
    TO* __restrict__ C,
    int N, int K, int NXT,
    float* __restrict__ sq)
{
    __shared__ __hip_bfloat16 As[128 * 32];
    __shared__ __hip_bfloat16 Bs[128 * 32];
    const int t = threadIdx.x;
    const int w = t >> 6, lane = t & 63;
    const int r16 = lane & 15, quad = lane >> 4;
    // XCD swizzle decode
    const int bx  = blockIdx.x;
    const int xcd = bx & 7, seq = bx >> 3;
    const int n_t = seq % NXT, m_t = seq / NXT;
    const int m0 = (xcd + 8 * m_t) * 128;
    const int n0 = n_t * 128;
    const int wm = w >> 1, wn = w & 1;
    const int srow = lane >> 2;          // 0..15 within a 16-row chunk
    const int scol = (lane & 3) * 8;     // element col within 32

    f32x4 acc[4][4];
    #pragma unroll
    for (int mi = 0; mi < 4; ++mi)
        #pragma unroll
        for (int ni = 0; ni < 4; ++ni)
            acc[mi][ni] = (f32x4){0.f, 0.f, 0.f, 0.f};

    for (int k0 = 0; k0 < K; k0 += 32) {
        #pragma unroll
        for (int p = 0; p < 2; ++p) {
            int row = w * 32 + p * 16 + srow;
            gl_lds16(A  + (size_t)(m0 + row) * K + k0 + scol, &As[row * 32 + scol]);
            gl_lds16(Bw + (size_t)(n0 + row) * K + k0 + scol, &Bs[row * 32 + scol]);
        }
        __syncthreads();   // drains vmcnt (incl. global_load_lds) + lgkm
        bf16x8 af[4], bfr[4];
        #pragma unroll
        for (int mi = 0; mi < 4; ++mi)
            af[mi] = *(const bf16x8*)&As[(wm * 64 + mi * 16 + r16) * 32 + quad * 8];
        #pragma unroll
        for (int ni = 0; ni < 4; ++ni)
            bfr[ni] = *(const bf16x8*)&Bs[(wn * 64 + ni * 16 + r16) * 32 + quad * 8];
        #pragma unroll
        for (int mi = 0; mi < 4; ++mi)
            #pragma unroll
            for (int ni = 0; ni < 4; ++ni)
                acc[mi][ni] = __builtin_amdgcn_mfma_f32_16x16x32_bf16(af[mi], bfr[ni], acc[mi][ni], 0, 0, 0);
        __syncthreads();
    }

    #pragma unroll
    for (int ni = 0; ni < 4; ++ni) {
        int col = n0 + wn * 64 + ni * 16 + r16;
        float bv = bias[col];
        float s = 0.f;
        #pragma unroll
        for (int mi = 0; mi < 4; ++mi) {
            #pragma unroll
            for (int reg = 0; reg < 4; ++reg) {
                int row = m0 + wm * 64 + mi * 16 + quad * 4 + reg;
                float o = acc[mi][ni][reg] + bv;
                storef(&C[(size_t)row * N + col], o);
                s += o * o;
            }
        }
        if (sq != nullptr && col < 768) {
            // same col across all 4 quads; reduce, then quad0 lanes atomic.
            s += __shfl_xor(s, 16);
            s += __shfl_xor(s, 32);
            if (quad == 0) {
                int b = m0 >> 12;   // 4096 rows per batch
                atomicAdd(&sq[b * 768 + col], s);
            }
        }
    }
}

__global__ void invnorm_kernel(const float* __restrict__ sumsq, float* __restrict__ invn)
{
    int i = blockIdx.x * 256 + threadIdx.x;
    if (i < 6144) invn[i] = 1.f / fmaxf(sqrtf(sumsq[i]), 1e-12f);
}

// ---------------------------------------------------------------------------
// G[bh] = k^T v  via MFMA.  Grid (4, 64): each block covers 1024 of L for one
// (b,h). 4 waves on disjoint 32-l chunks; k,v tiles staged TRANSPOSED in LDS.
// ---------------------------------------------------------------------------
__global__ __launch_bounds__(256) void ktv_mfma_kernel(
    const __hip_bfloat16* __restrict__ qkv, float* __restrict__ G)
{
    __shared__ __hip_bfloat16 kT[4][48][40];
    __shared__ __hip_bfloat16 vT[4][48][40];
    __shared__ float red[4][48][49];   // +1 pad: quad rows land on distinct banks

    const int bh = blockIdx.y; const int b = bh >> 3; const int h = bh & 7;
    const int lbase = blockIdx.x * 1024;
    const int t = threadIdx.x;
    const int w = t >> 6, lane = t & 63;
    const int r16 = lane & 15, quad = lane >> 4;

    f32x4 acc[3][3];
    #pragma unroll
    for (int mi = 0; mi < 3; ++mi)
        #pragma unroll
        for (int ni = 0; ni < 3; ++ni)
            acc[mi][ni] = (f32x4){0.f, 0.f, 0.f, 0.f};

    const int mat  = t & 1;        // 0 = k, 1 = v
    const int lrow = t >> 1;       // 0..127
    const int tile = lrow >> 5, l_in = lrow & 31;
    const __hip_bfloat16* src = qkv + 384 + mat * 384 + h * 48;
    __hip_bfloat16* dstT = (mat ? &vT[0][0][0] : &kT[0][0][0]) + ((size_t)tile * 48 * 40 + l_in);

    for (int it = 0; it < 8; ++it) {
        const int l0 = lbase + it * 128;
        const __hip_bfloat16* p = src + (size_t)(b * 4096 + l0 + lrow) * 1152;
        __hip_bfloat16 row[48];
        #pragma unroll
        for (int j = 0; j < 6; ++j) {
            uint4 v = *(const uint4*)(p + j * 8);
            __builtin_memcpy(&row[j * 8], &v, 16);
        }
        #pragma unroll
        for (int d = 0; d < 48; ++d)
            dstT[d * 40] = row[d];
        __syncthreads();

        bf16x8 af[3], bfr[3];
        #pragma unroll
        for (int mi = 0; mi < 3; ++mi)
            af[mi] = *(const bf16x8*)&kT[w][mi * 16 + r16][quad * 8];
        #pragma unroll
        for (int ni = 0; ni < 3; ++ni)
            bfr[ni] = *(const bf16x8*)&vT[w][ni * 16 + r16][quad * 8];
        #pragma unroll
        for (int mi = 0; mi < 3; ++mi)
            #pragma unroll
            for (int ni = 0; ni < 3; ++ni)
                acc[mi][ni] = __builtin_amdgcn_mfma_f32_16x16x32_bf16(af[mi], bfr[ni], acc[mi][ni], 0, 0, 0);
        __syncthreads();
    }

    #pragma unroll
    for (int mi = 0; mi < 3; ++mi)
        #pragma unroll
        for (int ni = 0; ni < 3; ++ni)
            #pragma unroll
            for (int reg = 0; reg < 4; ++reg)
                red[w][mi * 16 + quad * 4 + reg][ni * 16 + r16] = acc[mi][ni][reg];
    __syncthreads();

    float* Gb = G + (size_t)bh * 2304;
    for (int cell = t; cell < 2304; cell += 256) {
        int row = cell / 48, col = cell % 48;
        float s = red[0][row][col] + red[1][row][col] + red[2][row][col] + red[3][row][col];
        atomicAdd(&Gb[cell], s);
    }
}

// ---------------------------------------------------------------------------
// attn = G * invnorm_k[d] * temp[h] -> fp32 out;  attn2 = attn * invnorm_q[d]
// ---------------------------------------------------------------------------
__global__ void scale_attn_kernel(
    const float* __restrict__ G, const float* __restrict__ invn,
    const float* __restrict__ temp,
    float* __restrict__ attn_out, float* __restrict__ attn2)
{
    int bh = blockIdx.x; int b = bh >> 3; int h = bh & 7;
    float tf = temp[h];
    int t = threadIdx.x;
    for (int e = t; e < 2304; e += 256) {
        int dk = e / 48;
        float ink = invn[b * 768 + 384 + h * 48 + dk];
        float inq = invn[b * 768 + h * 48 + dk];
        float av  = G[(size_t)bh * 2304 + e] * ink * tf;
        attn_out[(size_t)bh * 2304 + e] = av;
        attn2[(size_t)bh * 2304 + e]    = av * inq;
    }
}

// ---------------------------------------------------------------------------
// y[b,l,h*48+e] = sum_d q[b,h,l,d]*attn2[d,e] + lepe(v)  — MFMA version.
// ---------------------------------------------------------------------------
__global__ __launch_bounds__(256) void qattn_lepe_mfma(
    const __hip_bfloat16* __restrict__ qkv, const float* __restrict__ attn2,
    const float* __restrict__ conv_w, const float* __restrict__ conv_b,
    __hip_bfloat16* __restrict__ y)
{
    __shared__ __attribute__((aligned(16))) char smem[26624];
    __hip_bfloat16 (*qs)[72]  = (__hip_bfloat16 (*)[72])smem;            // [128][72]
    __hip_bfloat16 (*a2s)[72] = (__hip_bfloat16 (*)[72])(smem + 18432);  // [48][72]
    float (*ys)[52]           = (float (*)[52])smem;                     // [128][52]
    __shared__ __hip_bfloat16 vs[4][64][48];   // 24576 B
    __shared__ float cwT[9][48];
    __shared__ float cb[48];

    const int bh = blockIdx.y; const int b = bh >> 3; const int h = bh & 7;
    const int yi0 = blockIdx.x * 2;            // first image row of this block
    const int l0  = yi0 * 64;                  // first L index
    const int t = threadIdx.x;
    const int w = t >> 6, lane = t & 63;
    const int r16 = lane & 15, quad = lane >> 4;

    // ---- stage q tile (128 x 48, k-pad 48..63 = 0) ----
    const __hip_bfloat16* qbase = qkv + (size_t)(b * 4096 + l0) * 1152 + h * 48;
    #pragma unroll
    for (int i = 0; i < 3; ++i) {
        int chunk = t + i * 256;               // 768 chunks
        int row = chunk / 6, cg = chunk % 6;
        *(bf16x8*)&qs[row][cg * 8] = load8(qbase + (size_t)row * 1152 + cg * 8);
    }
    *(bf16x8*)&qs[t >> 1][48 + (t & 1) * 8] = (bf16x8)0;   // zero pad k 48..63

    // ---- stage attn2 transposed: a2s[e][d] (bf16, k-pad 48..63 = 0) ----
    const float* a2g = attn2 + (size_t)bh * 2304;
    for (int i = t; i < 3072; i += 256) {
        int e = i >> 6, dd = i & 63;
        float val = (dd < 48) ? a2g[dd * 48 + e] : 0.f;
        a2s[e][dd] = __float2bfloat16(val);
    }

    // ---- stage v image rows yi0-1 .. yi0+2 (zeros outside image) ----
    const __hip_bfloat16* vbase = qkv + (size_t)b * 4096 * 1152 + 768 + h * 48;
    #pragma unroll
    for (int i = 0; i < 6; ++i) {
        int chunk = t + i * 256;               // 1536 chunks
        int r = chunk / 384, rem = chunk % 384;
        int xx = rem / 6, cg = rem % 6;
        int yy = yi0 - 1 + r;
        bf16x8 v = (yy >= 0 && yy < 64)
            ? load8(vbase + (size_t)(yy * 64 + xx) * 1152 + cg * 8)
            : (bf16x8)0;
        *(bf16x8*)&vs[r][xx][cg * 8] = v;
    }

    // ---- conv weights (transposed) + bias ----
    for (int i = t; i < 432; i += 256)
        cwT[i / 48][i % 48] = conv_w[(h * 48 + (i % 48)) * 9 + (i / 48)];
    if (t < 48) cb[t] = conv_b[h * 48 + t];
    __syncthreads();

    // ---- MFMA: wave w computes rows w*32..w*32+31 ----
    f32x4 acc[2][3];
    #pragma unroll
    for (int mi = 0; mi < 2; ++mi)
        #pragma unroll
        for (int ni = 0; ni < 3; ++ni)
            acc[mi][ni] = (f32x4){0.f, 0.f, 0.f, 0.f};
    #pragma unroll
    for (int ks = 0; ks < 2; ++ks) {
        int kb = ks * 32 + quad * 8;
        bf16x8 af[2], bfr[3];
        #pragma unroll
        for (int mi = 0; mi < 2; ++mi)
            af[mi] = *(const bf16x8*)&qs[w * 32 + mi * 16 + r16][kb];
        #pragma unroll
        for (int ni = 0; ni < 3; ++ni)
            bfr[ni] = *(const bf16x8*)&a2s[ni * 16 + r16][kb];
        #pragma unroll
        for (int mi = 0; mi < 2; ++mi)
            #pragma unroll
            for (int ni = 0; ni < 3; ++ni)
                acc[mi][ni] = __builtin_amdgcn_mfma_f32_16x16x32_bf16(af[mi], bfr[ni], acc[mi][ni], 0, 0, 0);
    }
    __syncthreads();   // all waves done reading qs/a2s — safe to alias as ys

    // ---- write matmul result to ys (C/D layout: col=lane&15, row=quad*4+reg)
    #pragma unroll
    for (int mi = 0; mi < 2; ++mi)
        #pragma unroll
        for (int ni = 0; ni < 3; ++ni)
            #pragma unroll
            for (int reg = 0; reg < 4; ++reg)
                ys[w * 32 + mi * 16 + quad * 4 + reg][ni * 16 + r16] = acc[mi][ni][reg];
    __syncthreads();

    // ---- conv + bias + store (channel-vectorized, 8 ch per group) ----
    __hip_bfloat16* ybase = y + (size_t)(b * 4096 + l0) * 384 + h * 48;
    #pragma unroll
    for (int i = 0; i < 3; ++i) {
        int g = t + i * 256;                   // 768 groups
        int l_in = g / 6, cg = g % 6, e0 = cg * 8;
        int xi = l_in & 63, vr0 = l_in >> 6;   // local image col / base v-row
        float o[8];
        #pragma unroll
        for (int j = 0; j < 8; ++j) o[j] = ys[l_in][e0 + j] + cb[e0 + j];
        #pragma unroll
        for (int dy = 0; dy < 3; ++dy) {
            #pragma unroll
            for (int dx = 0; dx < 3; ++dx) {
                int xx = xi + dx - 1;
                if (xx < 0 || xx > 63) continue;
                bf16x8 vv = *(const bf16x8*)&vs[vr0 + dy][xx][e0];
                const float* cwp = &cwT[dy * 3 + dx][e0];
                #pragma unroll
                for (int j = 0; j < 8; ++j) o[j] += b2f(vv[j]) * cwp[j];
            }
        }
        __hip_bfloat16 ob[8];
        #pragma unroll
        for (int j = 0; j < 8; ++j) ob[j] = __float2bfloat16(o[j]);
        uint4 pk; __builtin_memcpy(&pk, ob, 16);
        *(uint4*)(ybase + (size_t)l_in * 384 + e0) = pk;
    }
}

// ---------------------------------------------------------------------------
extern "C" void kernel_launch(void* const* d_in, const int* in_sizes, int n_in,
                              void* d_out, int out_size, void* d_ws, size_t ws_size,
                              hipStream_t stream)
{
    const float* x      = (const float*)d_in[0];
    const float* qkv_w  = (const float*)d_in[1];
    const float* qkv_b  = (const float*)d_in[2];
    const float* proj_w = (const float*)d_in[3];
    const float* proj_b = (const float*)d_in[4];
    const float* temp   = (const float*)d_in[5];
    const float* conv_w = (const float*)d_in[6];
    const float* conv_b = (const float*)d_in[7];

    char* ws = (char*)d_ws;
    __hip_bfloat16* qkv = (__hip_bfloat16*)(ws);                 // 75,497,472 B
    __hip_bfloat16* yb  = (__hip_bfloat16*)(ws + 75497472);      // 25,165,824 B
    float* sumsq = (float*)(ws + 100663296);                     // 24,576 B
    float* G     = (float*)(ws + 100687872);                     // 589,824 B
    float* invn  = (float*)(ws + 101277696);                     // 24,576 B
    float* attn2 = (float*)(ws + 101302272);                     // 589,824 B
    // x_bf16 aliases yb (dead until qattn_lepe); weight bf16 copies appended
    __hip_bfloat16* x_bf16  = yb;
    __hip_bfloat16* qkv_wb  = (__hip_bfloat16*)(ws + 101892096); // 884,736 B
    __hip_bfloat16* proj_wb = (__hip_bfloat16*)(ws + 102776832); // 294,912 B

    float* out      = (float*)d_out;
    float* attn_out = out + 12582912;

    // zero the atomic accumulators (sumsq + G are contiguous)
    (void)hipMemsetAsync(ws + 100663296, 0, 614400, stream);

    // 0) convert x, qkv_w, proj_w to bf16
    cvt_kernel<<<6432, 256, 0, stream>>>(x, x_bf16, qkv_w, qkv_wb, proj_w, proj_wb);
    // 1) qkv = x @ qkv_w^T + qkv_b  (bf16 -> bf16), fused q/k column sumsq
    gemm_bf16_nt<__hip_bfloat16><<<2304, 256, 0, stream>>>(
        x_bf16, qkv_wb, qkv_b, qkv, 1152, 384, 9, sumsq);
    // 2) invnorm from fused sumsq
    invnorm_kernel<<<24, 256, 0, stream>>>(sumsq, invn);
    // 3) G = k^T v  (MFMA)
    ktv_mfma_kernel<<<dim3(4, 64), 256, 0, stream>>>(qkv, G);
    // 4) attn (fp32 out) + attn2 (fp32, q-norm folded)
    scale_attn_kernel<<<64, 256, 0, stream>>>(G, invn, temp, attn_out, attn2);
    // 5) y = q @ attn2 + lepe   (MFMA, bf16 out — overwrites x_bf16 alias)
    qattn_lepe_mfma<<<dim3(32, 64), 256, 0, stream>>>(qkv, attn2, conv_w, conv_b, yb);
    // 6) out = y @ proj_w^T + proj_b   (bf16 -> fp32)
    gemm_bf16_nt<float><<<768, 256, 0, stream>>>(
        yb, proj_wb, proj_b, out, 384, 384, 3, nullptr);
}

// Round 8
// 230.995 us; speedup vs baseline: 2.4823x; 1.1118x over previous
//
#include <hip/hip_runtime.h>
#include <hip/hip_bf16.h>

// B=8, L=4096, C=384, h=8, d=48, H=W=64
// Inputs/outputs fp32 (per reference). Internals: x/weights pre-converted to
// bf16 (ws), qkv/y bf16 (ws), sumsq/G/invnorm/attn2 fp32 (ws).

typedef __bf16 bf16x8 __attribute__((ext_vector_type(8)));
typedef float f32x4 __attribute__((ext_vector_type(4)));

__device__ inline __bf16 f2b(float f) {
    __hip_bfloat16 h = __float2bfloat16(f);
    __bf16 r; __builtin_memcpy(&r, &h, 2); return r;
}
__device__ inline float b2f(__hip_bfloat16 h) { return __bfloat162float(h); }
__device__ inline float b2f(__bf16 v) {
    __hip_bfloat16 h; __builtin_memcpy(&h, &v, 2); return __bfloat162float(h);
}

__device__ inline bf16x8 load8(const __hip_bfloat16* p) {
    uint4 v = *(const uint4*)p;
    bf16x8 r; __builtin_memcpy(&r, &v, 16); return r;
}
__device__ inline bf16x8 load8(const float* p) {
    float4 a = *(const float4*)p;
    float4 b = *(const float4*)(p + 4);
    bf16x8 r;
    r[0] = f2b(a.x); r[1] = f2b(a.y); r[2] = f2b(a.z); r[3] = f2b(a.w);
    r[4] = f2b(b.x); r[5] = f2b(b.y); r[6] = f2b(b.z); r[7] = f2b(b.w);
    return r;
}

__device__ inline void storef(float* p, float v) { *p = v; }
__device__ inline void storef(__hip_bfloat16* p, float v) { *p = __float2bfloat16(v); }

// async 16B global -> LDS (wave-uniform base + lane*16 dest required)
__device__ inline void gl_lds16(const __hip_bfloat16* g, __hip_bfloat16* l) {
    __builtin_amdgcn_global_load_lds(
        (const __attribute__((address_space(1))) void*)g,
        (__attribute__((address_space(3))) void*)l,
        16, 0, 0);
}

// ---------------------------------------------------------------------------
// fp32 -> bf16 conversion: x (6144 blocks), qkv_w (216), proj_w (72)
// ---------------------------------------------------------------------------
__global__ __launch_bounds__(256) void cvt_kernel(
    const float* __restrict__ x,  __hip_bfloat16* __restrict__ xb,
    const float* __restrict__ qw, __hip_bfloat16* __restrict__ qwb,
    const float* __restrict__ pw, __hip_bfloat16* __restrict__ pwb)
{
    int blk = blockIdx.x;
    const float* src; __hip_bfloat16* dst; int base;
    if (blk < 6144)      { src = x;  dst = xb;  base = blk; }
    else if (blk < 6360) { src = qw; dst = qwb; base = blk - 6144; }
    else                 { src = pw; dst = pwb; base = blk - 6360; }
    int i = base * 256 + threadIdx.x;
    bf16x8 v = load8(src + (size_t)i * 8);
    *(bf16x8*)(dst + (size_t)i * 8) = v;
}

// ---------------------------------------------------------------------------
// GEMM: C[M,N] = A[M,K] @ Bw[N,K]^T + bias[N], bf16 in, fp32 accum.
// Block tile 128x64, BK=64, 6 k-iters (K=384). 4 waves, each 64x32
// (4x2 MFMA 16x16x32, 32 AGPR acc -> ~5 waves/SIMD residency).
// Staging via global_load_lds width-16 (dest lane-contiguous as required);
// the GLOBAL source chunk is XOR-swizzled (chunk ^ (row&7)) so the logical
// LDS layout is bank-conflict-free on ds_read_b128 fragment reads.
// 1-D grid, XCD swizzle: all NXT col-tiles of one row-tile on one XCD.
// Optional fused column sum-of-squares (cols < 768) into sq via atomics.
// ---------------------------------------------------------------------------
template <typename TO, int KC, bool FUSE_SQ>
__global__ __launch_bounds__(256) void gemm_bf16_nt(
    const __hip_bfloat16* __restrict__ A,
    const __hip_bfloat16* __restrict__ Bw,
    const float* __restrict__ bias,
    TO* __restrict__ C,
    int N, int NXT,
    float* __restrict__ sq)
{
    __shared__ __hip_bfloat16 As[128 * 64];   // 16 KB
    __shared__ __hip_bfloat16 Bs[64 * 64];    //  8 KB
    const int t = threadIdx.x;
    const int w = t >> 6, lane = t & 63;
    const int r16 = lane & 15, quad = lane >> 4;
    const int bx  = blockIdx.x;
    const int xcd = bx & 7, seq = bx >> 3;
    const int n_t = seq % NXT, m_t = seq / NXT;
    const int m0 = (xcd + 8 * m_t) * 128;
    const int n0 = n_t * 64;
    const int wm = w >> 1, wn = w & 1;

    f32x4 acc[4][2];
    #pragma unroll
    for (int mi = 0; mi < 4; ++mi)
        #pragma unroll
        for (int ni = 0; ni < 2; ++ni)
            acc[mi][ni] = (f32x4){0.f, 0.f, 0.f, 0.f};

    for (int k0 = 0; k0 < KC; k0 += 64) {
        // A: wave w stages rows [w*32, w*32+32), 8 chunks(16B)/row, 4/lane.
        // LDS dest chunk P = w*256 + p*64 + lane (contiguous); global source
        // column-chunk = (P&7) ^ (row&7)  [XOR swizzle].
        #pragma unroll
        for (int p = 0; p < 4; ++p) {
            int c = p * 64 + lane;                    // 0..255
            int rl = c >> 3;                          // row within wave's 32
            int cc = (c & 7) ^ (rl & 7);              // swizzled col chunk
            gl_lds16(A + (size_t)(m0 + w * 32 + rl) * KC + k0 + cc * 8,
                     &As[(w * 256 + c) * 8]);
        }
        // B: wave w stages rows [w*16, w*16+16), 2/lane.
        #pragma unroll
        for (int p = 0; p < 2; ++p) {
            int c = p * 64 + lane;                    // 0..127
            int rl = c >> 3;                          // row within wave's 16
            int cc = (c & 7) ^ (rl & 7);
            gl_lds16(Bw + (size_t)(n0 + w * 16 + rl) * KC + k0 + cc * 8,
                     &Bs[(w * 128 + c) * 8]);
        }
        __syncthreads();   // drains vmcnt (incl. global_load_lds)
        bf16x8 af[4][2], bfr[2][2];
        #pragma unroll
        for (int ks = 0; ks < 2; ++ks) {
            #pragma unroll
            for (int mi = 0; mi < 4; ++mi) {
                int row = wm * 64 + mi * 16 + r16;
                int pc  = (ks * 4 + quad) ^ (r16 & 7);   // physical chunk
                af[mi][ks] = *(const bf16x8*)&As[row * 64 + pc * 8];
            }
            #pragma unroll
            for (int ni = 0; ni < 2; ++ni) {
                int row = wn * 32 + ni * 16 + r16;
                int pc  = (ks * 4 + quad) ^ (r16 & 7);
                bfr[ni][ks] = *(const bf16x8*)&Bs[row * 64 + pc * 8];
            }
        }
        #pragma unroll
        for (int ks = 0; ks < 2; ++ks)
            #pragma unroll
            for (int mi = 0; mi < 4; ++mi)
                #pragma unroll
                for (int ni = 0; ni < 2; ++ni)
                    acc[mi][ni] = __builtin_amdgcn_mfma_f32_16x16x32_bf16(
                        af[mi][ks], bfr[ni][ks], acc[mi][ni], 0, 0, 0);
        __syncthreads();
    }

    #pragma unroll
    for (int ni = 0; ni < 2; ++ni) {
        int col = n0 + wn * 32 + ni * 16 + r16;
        float bv = bias[col];
        float s = 0.f;
        #pragma unroll
        for (int mi = 0; mi < 4; ++mi) {
            #pragma unroll
            for (int reg = 0; reg < 4; ++reg) {
                int row = m0 + wm * 64 + mi * 16 + quad * 4 + reg;
                float o = acc[mi][ni][reg] + bv;
                storef(&C[(size_t)row * N + col], o);
                s += o * o;
            }
        }
        if constexpr (FUSE_SQ) {
            if (col < 768) {
                s += __shfl_xor(s, 16);
                s += __shfl_xor(s, 32);
                if (quad == 0) {
                    int b = m0 >> 12;   // 4096 rows per batch
                    atomicAdd(&sq[b * 768 + col], s);
                }
            }
        }
    }
}

__global__ void invnorm_kernel(const float* __restrict__ sumsq, float* __restrict__ invn)
{
    int i = blockIdx.x * 256 + threadIdx.x;
    if (i < 6144) invn[i] = 1.f / fmaxf(sqrtf(sumsq[i]), 1e-12f);
}

// ---------------------------------------------------------------------------
// G[bh] = k^T v  via MFMA.  Grid (4, 64): each block covers 1024 of L for one
// (b,h). 4 waves on disjoint 32-l chunks; k,v tiles staged TRANSPOSED in LDS.
// ---------------------------------------------------------------------------
__global__ __launch_bounds__(256) void ktv_mfma_kernel(
    const __hip_bfloat16* __restrict__ qkv, float* __restrict__ G)
{
    __shared__ __hip_bfloat16 kT[4][48][40];
    __shared__ __hip_bfloat16 vT[4][48][40];
    __shared__ float red[4][48][49];   // +1 pad: quad rows land on distinct banks

    const int bh = blockIdx.y; const int b = bh >> 3; const int h = bh & 7;
    const int lbase = blockIdx.x * 1024;
    const int t = threadIdx.x;
    const int w = t >> 6, lane = t & 63;
    const int r16 = lane & 15, quad = lane >> 4;

    f32x4 acc[3][3];
    #pragma unroll
    for (int mi = 0; mi < 3; ++mi)
        #pragma unroll
        for (int ni = 0; ni < 3; ++ni)
            acc[mi][ni] = (f32x4){0.f, 0.f, 0.f, 0.f};

    const int mat  = t & 1;        // 0 = k, 1 = v
    const int lrow = t >> 1;       // 0..127
    const int tile = lrow >> 5, l_in = lrow & 31;
    const __hip_bfloat16* src = qkv + 384 + mat * 384 + h * 48;
    __hip_bfloat16* dstT = (mat ? &vT[0][0][0] : &kT[0][0][0]) + ((size_t)tile * 48 * 40 + l_in);

    for (int it = 0; it < 8; ++it) {
        const int l0 = lbase + it * 128;
        const __hip_bfloat16* p = src + (size_t)(b * 4096 + l0 + lrow) * 1152;
        __hip_bfloat16 row[48];
        #pragma unroll
        for (int j = 0; j < 6; ++j) {
            uint4 v = *(const uint4*)(p + j * 8);
            __builtin_memcpy(&row[j * 8], &v, 16);
        }
        #pragma unroll
        for (int d = 0; d < 48; ++d)
            dstT[d * 40] = row[d];
        __syncthreads();

        bf16x8 af[3], bfr[3];
        #pragma unroll
        for (int mi = 0; mi < 3; ++mi)
            af[mi] = *(const bf16x8*)&kT[w][mi * 16 + r16][quad * 8];
        #pragma unroll
        for (int ni = 0; ni < 3; ++ni)
            bfr[ni] = *(const bf16x8*)&vT[w][ni * 16 + r16][quad * 8];
        #pragma unroll
        for (int mi = 0; mi < 3; ++mi)
            #pragma unroll
            for (int ni = 0; ni < 3; ++ni)
                acc[mi][ni] = __builtin_amdgcn_mfma_f32_16x16x32_bf16(af[mi], bfr[ni], acc[mi][ni], 0, 0, 0);
        __syncthreads();
    }

    #pragma unroll
    for (int mi = 0; mi < 3; ++mi)
        #pragma unroll
        for (int ni = 0; ni < 3; ++ni)
            #pragma unroll
            for (int reg = 0; reg < 4; ++reg)
                red[w][mi * 16 + quad * 4 + reg][ni * 16 + r16] = acc[mi][ni][reg];
    __syncthreads();

    float* Gb = G + (size_t)bh * 2304;
    for (int cell = t; cell < 2304; cell += 256) {
        int row = cell / 48, col = cell % 48;
        float s = red[0][row][col] + red[1][row][col] + red[2][row][col] + red[3][row][col];
        atomicAdd(&Gb[cell], s);
    }
}

// ---------------------------------------------------------------------------
// attn = G * invnorm_k[d] * temp[h] -> fp32 out;  attn2 = attn * invnorm_q[d]
// ---------------------------------------------------------------------------
__global__ void scale_attn_kernel(
    const float* __restrict__ G, const float* __restrict__ invn,
    const float* __restrict__ temp,
    float* __restrict__ attn_out, float* __restrict__ attn2)
{
    int bh = blockIdx.x; int b = bh >> 3; int h = bh & 7;
    float tf = temp[h];
    int t = threadIdx.x;
    for (int e = t; e < 2304; e += 256) {
        int dk = e / 48;
        float ink = invn[b * 768 + 384 + h * 48 + dk];
        float inq = invn[b * 768 + h * 48 + dk];
        float av  = G[(size_t)bh * 2304 + e] * ink * tf;
        attn_out[(size_t)bh * 2304 + e] = av;
        attn2[(size_t)bh * 2304 + e]    = av * inq;
    }
}

// ---------------------------------------------------------------------------
// y[b,l,h*48+e] = sum_d q[b,h,l,d]*attn2[d,e] + lepe(v)  — MFMA version.
// ---------------------------------------------------------------------------
__global__ __launch_bounds__(256) void qattn_lepe_mfma(
    const __hip_bfloat16* __restrict__ qkv, const float* __restrict__ attn2,
    const float* __restrict__ conv_w, const float* __restrict__ conv_b,
    __hip_bfloat16* __restrict__ y)
{
    __shared__ __attribute__((aligned(16))) char smem[26624];
    __hip_bfloat16 (*qs)[72]  = (__hip_bfloat16 (*)[72])smem;            // [128][72]
    __hip_bfloat16 (*a2s)[72] = (__hip_bfloat16 (*)[72])(smem + 18432);  // [48][72]
    float (*ys)[52]           = (float (*)[52])smem;                     // [128][52]
    __shared__ __hip_bfloat16 vs[4][64][48];   // 24576 B
    __shared__ float cwT[9][48];
    __shared__ float cb[48];

    const int bh = blockIdx.y; const int b = bh >> 3; const int h = bh & 7;
    const int yi0 = blockIdx.x * 2;            // first image row of this block
    const int l0  = yi0 * 64;                  // first L index
    const int t = threadIdx.x;
    const int w = t >> 6, lane = t & 63;
    const int r16 = lane & 15, quad = lane >> 4;

    // ---- stage q tile (128 x 48, k-pad 48..63 = 0) ----
    const __hip_bfloat16* qbase = qkv + (size_t)(b * 4096 + l0) * 1152 + h * 48;
    #pragma unroll
    for (int i = 0; i < 3; ++i) {
        int chunk = t + i * 256;               // 768 chunks
        int row = chunk / 6, cg = chunk % 6;
        *(bf16x8*)&qs[row][cg * 8] = load8(qbase + (size_t)row * 1152 + cg * 8);
    }
    *(bf16x8*)&qs[t >> 1][48 + (t & 1) * 8] = (bf16x8)0;   // zero pad k 48..63

    // ---- stage attn2 transposed: a2s[e][d] (bf16, k-pad 48..63 = 0) ----
    const float* a2g = attn2 + (size_t)bh * 2304;
    for (int i = t; i < 3072; i += 256) {
        int e = i >> 6, dd = i & 63;
        float val = (dd < 48) ? a2g[dd * 48 + e] : 0.f;
        a2s[e][dd] = __float2bfloat16(val);
    }

    // ---- stage v image rows yi0-1 .. yi0+2 (zeros outside image) ----
    const __hip_bfloat16* vbase = qkv + (size_t)b * 4096 * 1152 + 768 + h * 48;
    #pragma unroll
    for (int i = 0; i < 6; ++i) {
        int chunk = t + i * 256;               // 1536 chunks
        int r = chunk / 384, rem = chunk % 384;
        int xx = rem / 6, cg = rem % 6;
        int yy = yi0 - 1 + r;
        bf16x8 v = (yy >= 0 && yy < 64)
            ? load8(vbase + (size_t)(yy * 64 + xx) * 1152 + cg * 8)
            : (bf16x8)0;
        *(bf16x8*)&vs[r][xx][cg * 8] = v;
    }

    // ---- conv weights (transposed) + bias ----
    for (int i = t; i < 432; i += 256)
        cwT[i / 48][i % 48] = conv_w[(h * 48 + (i % 48)) * 9 + (i / 48)];
    if (t < 48) cb[t] = conv_b[h * 48 + t];
    __syncthreads();

    // ---- MFMA: wave w computes rows w*32..w*32+31 ----
    f32x4 acc[2][3];
    #pragma unroll
    for (int mi = 0; mi < 2; ++mi)
        #pragma unroll
        for (int ni = 0; ni < 3; ++ni)
            acc[mi][ni] = (f32x4){0.f, 0.f, 0.f, 0.f};
    #pragma unroll
    for (int ks = 0; ks < 2; ++ks) {
        int kb = ks * 32 + quad * 8;
        bf16x8 af[2], bfr[3];
        #pragma unroll
        for (int mi = 0; mi < 2; ++mi)
            af[mi] = *(const bf16x8*)&qs[w * 32 + mi * 16 + r16][kb];
        #pragma unroll
        for (int ni = 0; ni < 3; ++ni)
            bfr[ni] = *(const bf16x8*)&a2s[ni * 16 + r16][kb];
        #pragma unroll
        for (int mi = 0; mi < 2; ++mi)
            #pragma unroll
            for (int ni = 0; ni < 3; ++ni)
                acc[mi][ni] = __builtin_amdgcn_mfma_f32_16x16x32_bf16(af[mi], bfr[ni], acc[mi][ni], 0, 0, 0);
    }
    __syncthreads();   // all waves done reading qs/a2s — safe to alias as ys

    // ---- write matmul result to ys (C/D layout: col=lane&15, row=quad*4+reg)
    #pragma unroll
    for (int mi = 0; mi < 2; ++mi)
        #pragma unroll
        for (int ni = 0; ni < 3; ++ni)
            #pragma unroll
            for (int reg = 0; reg < 4; ++reg)
                ys[w * 32 + mi * 16 + quad * 4 + reg][ni * 16 + r16] = acc[mi][ni][reg];
    __syncthreads();

    // ---- conv + bias + store (channel-vectorized, 8 ch per group) ----
    __hip_bfloat16* ybase = y + (size_t)(b * 4096 + l0) * 384 + h * 48;
    #pragma unroll
    for (int i = 0; i < 3; ++i) {
        int g = t + i * 256;                   // 768 groups
        int l_in = g / 6, cg = g % 6, e0 = cg * 8;
        int xi = l_in & 63, vr0 = l_in >> 6;   // local image col / base v-row
        float o[8];
        #pragma unroll
        for (int j = 0; j < 8; ++j) o[j] = ys[l_in][e0 + j] + cb[e0 + j];
        #pragma unroll
        for (int dy = 0; dy < 3; ++dy) {
            #pragma unroll
            for (int dx = 0; dx < 3; ++dx) {
                int xx = xi + dx - 1;
                if (xx < 0 || xx > 63) continue;
                bf16x8 vv = *(const bf16x8*)&vs[vr0 + dy][xx][e0];
                const float* cwp = &cwT[dy * 3 + dx][e0];
                #pragma unroll
                for (int j = 0; j < 8; ++j) o[j] += b2f(vv[j]) * cwp[j];
            }
        }
        __hip_bfloat16 ob[8];
        #pragma unroll
        for (int j = 0; j < 8; ++j) ob[j] = __float2bfloat16(o[j]);
        uint4 pk; __builtin_memcpy(&pk, ob, 16);
        *(uint4*)(ybase + (size_t)l_in * 384 + e0) = pk;
    }
}

// ---------------------------------------------------------------------------
extern "C" void kernel_launch(void* const* d_in, const int* in_sizes, int n_in,
                              void* d_out, int out_size, void* d_ws, size_t ws_size,
                              hipStream_t stream)
{
    const float* x      = (const float*)d_in[0];
    const float* qkv_w  = (const float*)d_in[1];
    const float* qkv_b  = (const float*)d_in[2];
    const float* proj_w = (const float*)d_in[3];
    const float* proj_b = (const float*)d_in[4];
    const float* temp   = (const float*)d_in[5];
    const float* conv_w = (const float*)d_in[6];
    const float* conv_b = (const float*)d_in[7];

    char* ws = (char*)d_ws;
    __hip_bfloat16* qkv = (__hip_bfloat16*)(ws);                 // 75,497,472 B
    __hip_bfloat16* yb  = (__hip_bfloat16*)(ws + 75497472);      // 25,165,824 B
    float* sumsq = (float*)(ws + 100663296);                     // 24,576 B
    float* G     = (float*)(ws + 100687872);                     // 589,824 B
    float* invn  = (float*)(ws + 101277696);                     // 24,576 B
    float* attn2 = (float*)(ws + 101302272);                     // 589,824 B
    // x_bf16 aliases yb (dead until qattn_lepe); weight bf16 copies appended
    __hip_bfloat16* x_bf16  = yb;
    __hip_bfloat16* qkv_wb  = (__hip_bfloat16*)(ws + 101892096); // 884,736 B
    __hip_bfloat16* proj_wb = (__hip_bfloat16*)(ws + 102776832); // 294,912 B

    float* out      = (float*)d_out;
    float* attn_out = out + 12582912;

    // zero the atomic accumulators (sumsq + G are contiguous)
    (void)hipMemsetAsync(ws + 100663296, 0, 614400, stream);

    // 0) convert x, qkv_w, proj_w to bf16
    cvt_kernel<<<6432, 256, 0, stream>>>(x, x_bf16, qkv_w, qkv_wb, proj_w, proj_wb);
    // 1) qkv = x @ qkv_w^T + qkv_b  (bf16 -> bf16), fused q/k column sumsq
    gemm_bf16_nt<__hip_bfloat16, 384, true><<<4608, 256, 0, stream>>>(
        x_bf16, qkv_wb, qkv_b, qkv, 1152, 18, sumsq);
    // 2) invnorm from fused sumsq
    invnorm_kernel<<<24, 256, 0, stream>>>(sumsq, invn);
    // 3) G = k^T v  (MFMA)
    ktv_mfma_kernel<<<dim3(4, 64), 256, 0, stream>>>(qkv, G);
    // 4) attn (fp32 out) + attn2 (fp32, q-norm folded)
    scale_attn_kernel<<<64, 256, 0, stream>>>(G, invn, temp, attn_out, attn2);
    // 5) y = q @ attn2 + lepe   (MFMA, bf16 out — overwrites x_bf16 alias)
    qattn_lepe_mfma<<<dim3(32, 64), 256, 0, stream>>>(qkv, attn2, conv_w, conv_b, yb);
    // 6) out = y @ proj_w^T + proj_b   (bf16 -> fp32)
    gemm_bf16_nt<float, 384, false><<<1536, 256, 0, stream>>>(
        yb, proj_wb, proj_b, out, 384, 6, nullptr);
}